// Round 1
// baseline (10184.254 us; speedup 1.0000x reference)
//
#include <hip/hip_runtime.h>
#include <hip/hip_bf16.h>
#include <cstdint>
#include <cstddef>

#define NNODES 100000
#define NEDGES 1600000
#define INCH 64
#define HID 128
#define NGRAPH 1024

// ---------------- weight transpose: W[j][k] -> Wt[k][j] ----------------
// wt pool layout (floats):
//   [0,      8192)  Wt_root0 [64][128]
//   [8192,  16384)  Wt_rel0  [64][128]
//   [16384, 65536)  Wt_rootR [3][128][128]
//   [65536,114688)  Wt_relR  [3][128][128]
//   [114688,122880) Wt_r1    [128][64]
__global__ __launch_bounds__(256) void transpose_weights_kernel(
    const float* __restrict__ Wroot0, const float* __restrict__ Wrel0,
    const float* __restrict__ WrootR, const float* __restrict__ WrelR,
    const float* __restrict__ Wr1, float* __restrict__ wt)
{
  int gid = blockIdx.x * 256 + threadIdx.x;
  float v;
  if (gid < 8192) {
    int j = gid & 127, k = gid >> 7;
    v = Wroot0[j * 64 + k];
  } else if (gid < 16384) {
    int m = gid - 8192;
    int j = m & 127, k = m >> 7;
    v = Wrel0[j * 64 + k];
  } else if (gid < 65536) {
    int m = gid - 16384;
    int l = m >> 14, mm = m & 16383;
    int j = mm & 127, k = mm >> 7;
    v = WrootR[l * 16384 + j * 128 + k];
  } else if (gid < 114688) {
    int m = gid - 65536;
    int l = m >> 14, mm = m & 16383;
    int j = mm & 127, k = mm >> 7;
    v = WrelR[l * 16384 + j * 128 + k];
  } else {
    int m = gid - 114688;
    int j = m & 63, k = m >> 6;
    v = Wr1[j * 128 + k];
  }
  wt[gid] = v;
}

// ---------------- edge scatter: agg[dst] += ew * x[src] ----------------
template <int D>
__global__ __launch_bounds__(256) void scatter_kernel(
    const int* __restrict__ ei, const float* __restrict__ ew,
    const float* __restrict__ x, float* __restrict__ agg)
{
  constexpr int C = D / 4;
  int gid = blockIdx.x * 256 + threadIdx.x;   // < E*C <= 51.2M
  int e = gid / C;
  int c = (gid % C) * 4;
  int src = ei[e];
  int dst = ei[NEDGES + e];
  float w = ew[e];
  const float4 v = *(const float4*)(x + (size_t)src * D + c);
  float* ap = agg + (size_t)dst * D + c;
  atomicAdd(ap + 0, w * v.x);
  atomicAdd(ap + 1, w * v.y);
  atomicAdd(ap + 2, w * v.z);
  atomicAdd(ap + 3, w * v.w);
}

// ---------------- tiled fp32 GEMM ----------------
// out[n][j] = bias[j] + sum_k A[n][k]*WtA[k][j] (+ sum_k B[n][k]*WtB[k][j]), opt relu
// Per-thread 4 nodes x 4 j. Safe to run in-place with out == A (writes only in
// epilogue, to rows this block alone staged).
__device__ inline void fma_acc4(float (&acc)[4], const float4 av,
                                const float4 w0, const float4 w1,
                                const float4 w2, const float4 w3)
{
  acc[0] += av.x * w0.x + av.y * w1.x + av.z * w2.x + av.w * w3.x;
  acc[1] += av.x * w0.y + av.y * w1.y + av.z * w2.y + av.w * w3.y;
  acc[2] += av.x * w0.z + av.y * w1.z + av.z * w2.z + av.w * w3.z;
  acc[3] += av.x * w0.w + av.y * w1.w + av.z * w2.w + av.w * w3.w;
}

template <int KDIM, int HOUT, bool DUAL, bool RELU>
__global__ __launch_bounds__(256) void gemm_kernel(
    const float* __restrict__ A, const float* __restrict__ WtA,
    const float* __restrict__ B, const float* __restrict__ WtB,
    const float* __restrict__ bias, float* __restrict__ out)
{
  constexpr int KC = 32;
  constexpr int SAP = KC + 4;           // padded LDS row (breaks bank aliasing)
  constexpr int JT = HOUT / 4;          // threads along j
  constexpr int NG = 256 / JT;          // node groups per block
  constexpr int NT = NG * 4;            // nodes per block (128->32, 64->64)

  __shared__ float sWa[KC * HOUT];
  __shared__ float sWb[DUAL ? KC * HOUT : 4];
  __shared__ float sA[NT * SAP];
  __shared__ float sB[DUAL ? NT * SAP : 4];

  const int tid = threadIdx.x;
  const int jt = tid % JT, j0 = jt * 4;
  const int ng = tid / JT, n0 = ng * 4;
  const int nbase = blockIdx.x * NT;

  float acc[4][4];
#pragma unroll
  for (int a = 0; a < 4; a++)
#pragma unroll
    for (int b = 0; b < 4; b++) acc[a][b] = 0.f;

  for (int k0 = 0; k0 < KDIM; k0 += KC) {
    // ---- stage weight chunk (contiguous in k-major transposed layout) ----
    {
      constexpr int WV = KC * HOUT / 4;  // float4 count (1024 or 512)
      const float4* ga = (const float4*)(WtA + (size_t)k0 * HOUT);
      float4* la = (float4*)sWa;
#pragma unroll
      for (int t = 0; t < WV / 256; t++) la[tid + t * 256] = ga[tid + t * 256];
      if (DUAL) {
        const float4* gb = (const float4*)(WtB + (size_t)k0 * HOUT);
        float4* lb = (float4*)sWb;
#pragma unroll
        for (int t = 0; t < WV / 256; t++) lb[tid + t * 256] = gb[tid + t * 256];
      }
    }
    // ---- stage activation chunk ----
    {
      constexpr int AV = NT * KC / 4;    // float4 count (256 or 512)
#pragma unroll
      for (int t = 0; t < AV / 256; t++) {
        int id = tid + t * 256;
        int n = id / (KC / 4);
        int kk4 = (id % (KC / 4)) * 4;
        int gn = nbase + n;
        float4 va = make_float4(0.f, 0.f, 0.f, 0.f);
        if (gn < NNODES) va = *(const float4*)(A + (size_t)gn * KDIM + k0 + kk4);
        *(float4*)(sA + n * SAP + kk4) = va;
        if (DUAL) {
          float4 vb = make_float4(0.f, 0.f, 0.f, 0.f);
          if (gn < NNODES) vb = *(const float4*)(B + (size_t)gn * KDIM + k0 + kk4);
          *(float4*)(sB + n * SAP + kk4) = vb;
        }
      }
    }
    __syncthreads();

    // ---- compute ----
#pragma unroll
    for (int kk = 0; kk < KC; kk += 4) {
      float4 wa0 = *(const float4*)(sWa + (kk + 0) * HOUT + j0);
      float4 wa1 = *(const float4*)(sWa + (kk + 1) * HOUT + j0);
      float4 wa2 = *(const float4*)(sWa + (kk + 2) * HOUT + j0);
      float4 wa3 = *(const float4*)(sWa + (kk + 3) * HOUT + j0);
      float4 wb0, wb1, wb2, wb3;
      if (DUAL) {
        wb0 = *(const float4*)(sWb + (kk + 0) * HOUT + j0);
        wb1 = *(const float4*)(sWb + (kk + 1) * HOUT + j0);
        wb2 = *(const float4*)(sWb + (kk + 2) * HOUT + j0);
        wb3 = *(const float4*)(sWb + (kk + 3) * HOUT + j0);
      }
#pragma unroll
      for (int nn = 0; nn < 4; nn++) {
        float4 av = *(const float4*)(sA + (n0 + nn) * SAP + kk);
        fma_acc4(acc[nn], av, wa0, wa1, wa2, wa3);
        if (DUAL) {
          float4 bv = *(const float4*)(sB + (n0 + nn) * SAP + kk);
          fma_acc4(acc[nn], bv, wb0, wb1, wb2, wb3);
        }
      }
    }
    __syncthreads();
  }

  // ---- epilogue ----
  float4 bs = *(const float4*)(bias + j0);
#pragma unroll
  for (int nn = 0; nn < 4; nn++) {
    int gn = nbase + n0 + nn;
    if (gn < NNODES) {
      float4 r;
      r.x = acc[nn][0] + bs.x;
      r.y = acc[nn][1] + bs.y;
      r.z = acc[nn][2] + bs.z;
      r.w = acc[nn][3] + bs.w;
      if (RELU) {
        r.x = fmaxf(r.x, 0.f); r.y = fmaxf(r.y, 0.f);
        r.z = fmaxf(r.z, 0.f); r.w = fmaxf(r.w, 0.f);
      }
      *(float4*)(out + (size_t)gn * HOUT + j0) = r;
    }
  }
}

// ---------------- readout stage 2: per-node dot + scatter-mean ----------------
__global__ __launch_bounds__(256) void readout2_kernel(
    const float* __restrict__ h, const float* __restrict__ Wr2,
    const float* __restrict__ br2, const int* __restrict__ batch,
    float* __restrict__ num, float* __restrict__ cnt)
{
  int node = blockIdx.x * 4 + (threadIdx.x >> 6);
  int lane = threadIdx.x & 63;
  if (node >= NNODES) return;
  float val = h[(size_t)node * 64 + lane] * Wr2[lane];
#pragma unroll
  for (int off = 32; off >= 1; off >>= 1) val += __shfl_xor(val, off, 64);
  if (lane == 0) {
    int g = batch[node];
    atomicAdd(&num[g], val + br2[0]);
    atomicAdd(&cnt[g], 1.0f);
  }
}

__global__ __launch_bounds__(256) void finalize_kernel(
    const float* __restrict__ num, const float* __restrict__ cnt,
    float* __restrict__ out)
{
  int g = blockIdx.x * 256 + threadIdx.x;
  if (g < NGRAPH) out[g] = num[g] / fmaxf(cnt[g], 1.0f);
}

// ---------------- launch ----------------
extern "C" void kernel_launch(void* const* d_in, const int* in_sizes, int n_in,
                              void* d_out, int out_size, void* d_ws, size_t ws_size,
                              hipStream_t stream)
{
  const float* x      = (const float*)d_in[0];
  const int*   ei     = (const int*)d_in[1];
  const float* ew     = (const float*)d_in[2];
  const int*   batch  = (const int*)d_in[3];
  const float* Wroot0 = (const float*)d_in[4];
  const float* Wrel0  = (const float*)d_in[5];
  const float* b0     = (const float*)d_in[6];
  const float* WrootR = (const float*)d_in[7];
  const float* WrelR  = (const float*)d_in[8];
  const float* bR     = (const float*)d_in[9];
  const float* Wr1    = (const float*)d_in[10];
  const float* br1    = (const float*)d_in[11];
  const float* Wr2    = (const float*)d_in[12];
  const float* br2    = (const float*)d_in[13];

  char* ws = (char*)d_ws;
  float* wt   = (float*)ws;                         // 122880 floats (<512KB)
  float* bufA = (float*)(ws + (1 << 19));           // N*128 f32 = 51.2MB
  float* bufB = bufA + (size_t)NNODES * HID;        // N*128 f32
  float* num  = bufB + (size_t)NNODES * HID;        // G
  float* cnt  = num + NGRAPH;                       // G

  transpose_weights_kernel<<<480, 256, 0, stream>>>(Wroot0, Wrel0, WrootR, WrelR, Wr1, wt);
  const float* wtRoot0 = wt;
  const float* wtRel0  = wt + 8192;
  const float* wtRootR = wt + 16384;
  const float* wtRelR  = wt + 65536;
  const float* wtR1    = wt + 114688;

  // ---- layer 0: IN=64 -> H=128 ----
  hipMemsetAsync(bufA, 0, (size_t)NNODES * INCH * sizeof(float), stream);
  scatter_kernel<64><<<NEDGES * (64 / 4) / 256, 256, 0, stream>>>(ei, ew, x, bufA);
  gemm_kernel<64, 128, true, false><<<(NNODES + 31) / 32, 256, 0, stream>>>(
      bufA, wtRel0, x, wtRoot0, b0, bufB);

  // ---- layers 1..3: H -> H (in-place GEMM over agg buffer) ----
  float* bufs[2] = { bufB, bufA };
  for (int l = 0; l < 3; l++) {
    float* in  = bufs[l & 1];
    float* agg = bufs[(l & 1) ^ 1];
    hipMemsetAsync(agg, 0, (size_t)NNODES * HID * sizeof(float), stream);
    scatter_kernel<128><<<NEDGES * (128 / 4) / 256, 256, 0, stream>>>(ei, ew, in, agg);
    gemm_kernel<128, 128, true, false><<<(NNODES + 31) / 32, 256, 0, stream>>>(
        agg, wtRelR + l * 16384, in, wtRootR + l * 16384, bR + l * 128, agg);
  }
  // y3 now in bufA

  // ---- readout: h = relu(y @ Wr1.T + br1) [N,64] -> bufB ----
  gemm_kernel<128, 64, false, true><<<(NNODES + 63) / 64, 256, 0, stream>>>(
      bufA, wtR1, nullptr, nullptr, br1, bufB);

  hipMemsetAsync(num, 0, 2 * NGRAPH * sizeof(float), stream);
  readout2_kernel<<<(NNODES + 3) / 4, 256, 0, stream>>>(bufB, Wr2, br2, batch, num, cnt);
  finalize_kernel<<<(NGRAPH + 255) / 256, 256, 0, stream>>>(num, cnt, (float*)d_out);
}

// Round 2
// 1335.816 us; speedup vs baseline: 7.6240x; 7.6240x over previous
//
#include <hip/hip_runtime.h>
#include <hip/hip_bf16.h>
#include <cstdint>
#include <cstddef>

#define NNODES 100000
#define NEDGES 1600000
#define INCH 64
#define HID 128
#define NGRAPH 1024
#define NB_SCAN ((NNODES + 255) / 256)   // 391

// ---------------- weight transpose: W[j][k] -> Wt[k][j] ----------------
__global__ __launch_bounds__(256) void transpose_weights_kernel(
    const float* __restrict__ Wroot0, const float* __restrict__ Wrel0,
    const float* __restrict__ WrootR, const float* __restrict__ WrelR,
    const float* __restrict__ Wr1, float* __restrict__ wt)
{
  int gid = blockIdx.x * 256 + threadIdx.x;
  float v;
  if (gid < 8192) {
    int j = gid & 127, k = gid >> 7;
    v = Wroot0[j * 64 + k];
  } else if (gid < 16384) {
    int m = gid - 8192;
    int j = m & 127, k = m >> 7;
    v = Wrel0[j * 64 + k];
  } else if (gid < 65536) {
    int m = gid - 16384;
    int l = m >> 14, mm = m & 16383;
    int j = mm & 127, k = mm >> 7;
    v = WrootR[l * 16384 + j * 128 + k];
  } else if (gid < 114688) {
    int m = gid - 65536;
    int l = m >> 14, mm = m & 16383;
    int j = mm & 127, k = mm >> 7;
    v = WrelR[l * 16384 + j * 128 + k];
  } else {
    int m = gid - 114688;
    int j = m & 63, k = m >> 6;
    v = Wr1[j * 128 + k];
  }
  wt[gid] = v;
}

// ---------------- CSR build ----------------
__global__ __launch_bounds__(256) void hist_kernel(
    const int* __restrict__ ei, int* __restrict__ deg)
{
  int e = blockIdx.x * 256 + threadIdx.x;
  if (e < NEDGES) atomicAdd(&deg[ei[NEDGES + e]], 1);
}

__global__ __launch_bounds__(256) void scan1_kernel(
    const int* __restrict__ deg, int* __restrict__ exloc, int* __restrict__ bsum)
{
  __shared__ int s[256];
  int i = blockIdx.x * 256 + threadIdx.x;
  int v = (i < NNODES) ? deg[i] : 0;
  s[threadIdx.x] = v;
  __syncthreads();
#pragma unroll
  for (int off = 1; off < 256; off <<= 1) {
    int t = (threadIdx.x >= off) ? s[threadIdx.x - off] : 0;
    __syncthreads();
    s[threadIdx.x] += t;
    __syncthreads();
  }
  if (i < NNODES) exloc[i] = s[threadIdx.x] - v;   // exclusive within block
  if (threadIdx.x == 255) bsum[blockIdx.x] = s[255];
}

__global__ __launch_bounds__(512) void scan2_kernel(int* __restrict__ bsum)
{
  __shared__ int s[512];
  int v = (threadIdx.x < NB_SCAN) ? bsum[threadIdx.x] : 0;
  s[threadIdx.x] = v;
  __syncthreads();
#pragma unroll
  for (int off = 1; off < 512; off <<= 1) {
    int t = (threadIdx.x >= off) ? s[threadIdx.x - off] : 0;
    __syncthreads();
    s[threadIdx.x] += t;
    __syncthreads();
  }
  if (threadIdx.x < NB_SCAN) bsum[threadIdx.x] = s[threadIdx.x] - v;  // exclusive
}

__global__ __launch_bounds__(256) void scan3_kernel(
    const int* __restrict__ exloc, const int* __restrict__ bsum,
    int* __restrict__ row_ptr, int* __restrict__ row_fill)
{
  int i = blockIdx.x * 256 + threadIdx.x;
  if (i < NNODES) {
    int v = exloc[i] + bsum[blockIdx.x];
    row_ptr[i] = v;
    row_fill[i] = v;
  }
  if (i == 0) row_ptr[NNODES] = NEDGES;
}

__global__ __launch_bounds__(256) void fill_kernel(
    const int* __restrict__ ei, const float* __restrict__ ew,
    int* __restrict__ row_fill, int* __restrict__ srcs, float* __restrict__ wgt)
{
  int e = blockIdx.x * 256 + threadIdx.x;
  if (e < NEDGES) {
    int d = ei[NEDGES + e];
    int p = atomicAdd(&row_fill[d], 1);
    srcs[p] = ei[e];
    wgt[p] = ew[e];
  }
}

// ---------------- gather aggregation (atomic-free) ----------------
// One wave per node; lane owns 2 (D=128) or 1 (D=64) features.
__global__ __launch_bounds__(256) void agg128_kernel(
    const int* __restrict__ row_ptr, const int* __restrict__ srcs,
    const float* __restrict__ wgt, const float* __restrict__ x,
    float* __restrict__ agg)
{
  int node = blockIdx.x * 4 + (threadIdx.x >> 6);
  int lane = threadIdx.x & 63;
  if (node >= NNODES) return;
  int i = row_ptr[node], end = row_ptr[node + 1];
  float2 acc = make_float2(0.f, 0.f);
  for (; i + 1 < end; i += 2) {
    int sa = srcs[i], sb = srcs[i + 1];
    float wa = wgt[i], wb = wgt[i + 1];
    float2 va = *(const float2*)(x + (size_t)sa * 128 + lane * 2);
    float2 vb = *(const float2*)(x + (size_t)sb * 128 + lane * 2);
    acc.x += wa * va.x + wb * vb.x;
    acc.y += wa * va.y + wb * vb.y;
  }
  if (i < end) {
    int sa = srcs[i];
    float wa = wgt[i];
    float2 va = *(const float2*)(x + (size_t)sa * 128 + lane * 2);
    acc.x += wa * va.x;
    acc.y += wa * va.y;
  }
  *(float2*)(agg + (size_t)node * 128 + lane * 2) = acc;
}

__global__ __launch_bounds__(256) void agg64_kernel(
    const int* __restrict__ row_ptr, const int* __restrict__ srcs,
    const float* __restrict__ wgt, const float* __restrict__ x,
    float* __restrict__ agg)
{
  int node = blockIdx.x * 4 + (threadIdx.x >> 6);
  int lane = threadIdx.x & 63;
  if (node >= NNODES) return;
  int i = row_ptr[node], end = row_ptr[node + 1];
  float acc = 0.f;
  for (; i + 1 < end; i += 2) {
    int sa = srcs[i], sb = srcs[i + 1];
    float wa = wgt[i], wb = wgt[i + 1];
    float va = x[(size_t)sa * 64 + lane];
    float vb = x[(size_t)sb * 64 + lane];
    acc += wa * va + wb * vb;
  }
  if (i < end) acc += wgt[i] * x[(size_t)srcs[i] * 64 + lane];
  agg[(size_t)node * 64 + lane] = acc;
}

// ---------------- tiled fp32 GEMM ----------------
__device__ inline void fma_acc4(float (&acc)[4], const float4 av,
                                const float4 w0, const float4 w1,
                                const float4 w2, const float4 w3)
{
  acc[0] += av.x * w0.x + av.y * w1.x + av.z * w2.x + av.w * w3.x;
  acc[1] += av.x * w0.y + av.y * w1.y + av.z * w2.y + av.w * w3.y;
  acc[2] += av.x * w0.z + av.y * w1.z + av.z * w2.z + av.w * w3.z;
  acc[3] += av.x * w0.w + av.y * w1.w + av.z * w2.w + av.w * w3.w;
}

template <int KDIM, int HOUT, bool DUAL, bool RELU>
__global__ __launch_bounds__(256) void gemm_kernel(
    const float* __restrict__ A, const float* __restrict__ WtA,
    const float* __restrict__ B, const float* __restrict__ WtB,
    const float* __restrict__ bias, float* __restrict__ out)
{
  constexpr int KC = 32;
  constexpr int SAP = KC + 4;
  constexpr int JT = HOUT / 4;
  constexpr int NG = 256 / JT;
  constexpr int NT = NG * 4;

  __shared__ float sWa[KC * HOUT];
  __shared__ float sWb[DUAL ? KC * HOUT : 4];
  __shared__ float sA[NT * SAP];
  __shared__ float sB[DUAL ? NT * SAP : 4];

  const int tid = threadIdx.x;
  const int jt = tid % JT, j0 = jt * 4;
  const int ng = tid / JT, n0 = ng * 4;
  const int nbase = blockIdx.x * NT;

  float acc[4][4];
#pragma unroll
  for (int a = 0; a < 4; a++)
#pragma unroll
    for (int b = 0; b < 4; b++) acc[a][b] = 0.f;

  for (int k0 = 0; k0 < KDIM; k0 += KC) {
    {
      constexpr int WV = KC * HOUT / 4;
      const float4* ga = (const float4*)(WtA + (size_t)k0 * HOUT);
      float4* la = (float4*)sWa;
#pragma unroll
      for (int t = 0; t < WV / 256; t++) la[tid + t * 256] = ga[tid + t * 256];
      if (DUAL) {
        const float4* gb = (const float4*)(WtB + (size_t)k0 * HOUT);
        float4* lb = (float4*)sWb;
#pragma unroll
        for (int t = 0; t < WV / 256; t++) lb[tid + t * 256] = gb[tid + t * 256];
      }
    }
    {
      constexpr int AV = NT * KC / 4;
#pragma unroll
      for (int t = 0; t < AV / 256; t++) {
        int id = tid + t * 256;
        int n = id / (KC / 4);
        int kk4 = (id % (KC / 4)) * 4;
        int gn = nbase + n;
        float4 va = make_float4(0.f, 0.f, 0.f, 0.f);
        if (gn < NNODES) va = *(const float4*)(A + (size_t)gn * KDIM + k0 + kk4);
        *(float4*)(sA + n * SAP + kk4) = va;
        if (DUAL) {
          float4 vb = make_float4(0.f, 0.f, 0.f, 0.f);
          if (gn < NNODES) vb = *(const float4*)(B + (size_t)gn * KDIM + k0 + kk4);
          *(float4*)(sB + n * SAP + kk4) = vb;
        }
      }
    }
    __syncthreads();

#pragma unroll
    for (int kk = 0; kk < KC; kk += 4) {
      float4 wa0 = *(const float4*)(sWa + (kk + 0) * HOUT + j0);
      float4 wa1 = *(const float4*)(sWa + (kk + 1) * HOUT + j0);
      float4 wa2 = *(const float4*)(sWa + (kk + 2) * HOUT + j0);
      float4 wa3 = *(const float4*)(sWa + (kk + 3) * HOUT + j0);
      float4 wb0, wb1, wb2, wb3;
      if (DUAL) {
        wb0 = *(const float4*)(sWb + (kk + 0) * HOUT + j0);
        wb1 = *(const float4*)(sWb + (kk + 1) * HOUT + j0);
        wb2 = *(const float4*)(sWb + (kk + 2) * HOUT + j0);
        wb3 = *(const float4*)(sWb + (kk + 3) * HOUT + j0);
      }
#pragma unroll
      for (int nn = 0; nn < 4; nn++) {
        float4 av = *(const float4*)(sA + (n0 + nn) * SAP + kk);
        fma_acc4(acc[nn], av, wa0, wa1, wa2, wa3);
        if (DUAL) {
          float4 bv = *(const float4*)(sB + (n0 + nn) * SAP + kk);
          fma_acc4(acc[nn], bv, wb0, wb1, wb2, wb3);
        }
      }
    }
    __syncthreads();
  }

  float4 bs = *(const float4*)(bias + j0);
#pragma unroll
  for (int nn = 0; nn < 4; nn++) {
    int gn = nbase + n0 + nn;
    if (gn < NNODES) {
      float4 r;
      r.x = acc[nn][0] + bs.x;
      r.y = acc[nn][1] + bs.y;
      r.z = acc[nn][2] + bs.z;
      r.w = acc[nn][3] + bs.w;
      if (RELU) {
        r.x = fmaxf(r.x, 0.f); r.y = fmaxf(r.y, 0.f);
        r.z = fmaxf(r.z, 0.f); r.w = fmaxf(r.w, 0.f);
      }
      *(float4*)(out + (size_t)gn * HOUT + j0) = r;
    }
  }
}

// ---------------- readout stage 2 + finalize ----------------
__global__ __launch_bounds__(256) void readout2_kernel(
    const float* __restrict__ h, const float* __restrict__ Wr2,
    const float* __restrict__ br2, const int* __restrict__ batch,
    float* __restrict__ num, float* __restrict__ cnt)
{
  int node = blockIdx.x * 4 + (threadIdx.x >> 6);
  int lane = threadIdx.x & 63;
  if (node >= NNODES) return;
  float val = h[(size_t)node * 64 + lane] * Wr2[lane];
#pragma unroll
  for (int off = 32; off >= 1; off >>= 1) val += __shfl_xor(val, off, 64);
  if (lane == 0) {
    int g = batch[node];
    atomicAdd(&num[g], val + br2[0]);
    atomicAdd(&cnt[g], 1.0f);
  }
}

__global__ __launch_bounds__(256) void finalize_kernel(
    const float* __restrict__ num, const float* __restrict__ cnt,
    float* __restrict__ out)
{
  int g = blockIdx.x * 256 + threadIdx.x;
  if (g < NGRAPH) out[g] = num[g] / fmaxf(cnt[g], 1.0f);
}

// ---------------- launch ----------------
extern "C" void kernel_launch(void* const* d_in, const int* in_sizes, int n_in,
                              void* d_out, int out_size, void* d_ws, size_t ws_size,
                              hipStream_t stream)
{
  const float* x      = (const float*)d_in[0];
  const int*   ei     = (const int*)d_in[1];
  const float* ew     = (const float*)d_in[2];
  const int*   batch  = (const int*)d_in[3];
  const float* Wroot0 = (const float*)d_in[4];
  const float* Wrel0  = (const float*)d_in[5];
  const float* b0     = (const float*)d_in[6];
  const float* WrootR = (const float*)d_in[7];
  const float* WrelR  = (const float*)d_in[8];
  const float* bR     = (const float*)d_in[9];
  const float* Wr1    = (const float*)d_in[10];
  const float* br1    = (const float*)d_in[11];
  const float* Wr2    = (const float*)d_in[12];
  const float* br2    = (const float*)d_in[13];

  char* ws = (char*)d_ws;
  float* wt   = (float*)ws;                          // 122880 floats, pad to 131072
  float* bufA = wt + 131072;                         // N*128 f32 = 51.2MB
  float* bufB = bufA + (size_t)NNODES * HID;         // N*128 f32 = 51.2MB
  float* num  = bufB + (size_t)NNODES * HID;         // G
  float* cnt  = num + NGRAPH;                        // G
  int*   deg      = (int*)(cnt + NGRAPH);            // N
  int*   exloc    = deg + NNODES;                    // N
  int*   row_ptr  = exloc + NNODES;                  // N+1
  int*   row_fill = row_ptr + NNODES + 2;            // N
  int*   bsum     = row_fill + NNODES;               // 512
  int*   srcs     = bsum + 512;                      // E
  float* wgt      = (float*)(srcs + NEDGES);         // E

  transpose_weights_kernel<<<480, 256, 0, stream>>>(Wroot0, Wrel0, WrootR, WrelR, Wr1, wt);
  const float* wtRoot0 = wt;
  const float* wtRel0  = wt + 8192;
  const float* wtRootR = wt + 16384;
  const float* wtRelR  = wt + 65536;
  const float* wtR1    = wt + 114688;

  // ---- CSR build (by dst) ----
  hipMemsetAsync(deg, 0, NNODES * sizeof(int), stream);
  hist_kernel<<<(NEDGES + 255) / 256, 256, 0, stream>>>(ei, deg);
  scan1_kernel<<<NB_SCAN, 256, 0, stream>>>(deg, exloc, bsum);
  scan2_kernel<<<1, 512, 0, stream>>>(bsum);
  scan3_kernel<<<NB_SCAN, 256, 0, stream>>>(exloc, bsum, row_ptr, row_fill);
  fill_kernel<<<(NEDGES + 255) / 256, 256, 0, stream>>>(ei, ew, row_fill, srcs, wgt);

  // ---- layer 0: IN=64 -> H=128 ----
  agg64_kernel<<<(NNODES + 3) / 4, 256, 0, stream>>>(row_ptr, srcs, wgt, x, bufA);
  gemm_kernel<64, 128, true, false><<<(NNODES + 31) / 32, 256, 0, stream>>>(
      bufA, wtRel0, x, wtRoot0, b0, bufB);

  // ---- layers 1..3: H -> H ----
  float* bufs[2] = { bufB, bufA };
  for (int l = 0; l < 3; l++) {
    float* in  = bufs[l & 1];
    float* agg = bufs[(l & 1) ^ 1];
    agg128_kernel<<<(NNODES + 3) / 4, 256, 0, stream>>>(row_ptr, srcs, wgt, in, agg);
    gemm_kernel<128, 128, true, false><<<(NNODES + 31) / 32, 256, 0, stream>>>(
        agg, wtRelR + l * 16384, in, wtRootR + l * 16384, bR + l * 128, agg);
  }
  // y3 in bufA

  // ---- readout ----
  gemm_kernel<128, 64, false, true><<<(NNODES + 63) / 64, 256, 0, stream>>>(
      bufA, wtR1, nullptr, nullptr, br1, bufB);

  hipMemsetAsync(num, 0, 2 * NGRAPH * sizeof(float), stream);
  readout2_kernel<<<(NNODES + 3) / 4, 256, 0, stream>>>(bufB, Wr2, br2, batch, num, cnt);
  finalize_kernel<<<(NGRAPH + 255) / 256, 256, 0, stream>>>(num, cnt, (float*)d_out);
}

// Round 3
// 1207.404 us; speedup vs baseline: 8.4348x; 1.1064x over previous
//
#include <hip/hip_runtime.h>
#include <hip/hip_bf16.h>
#include <cstdint>
#include <cstddef>

#define NNODES 100000
#define NEDGES 1600000
#define INCH 64
#define HID 128
#define NGRAPH 1024
#define NB_SCAN ((NNODES + 255) / 256)   // 391

// ---------------- weight transpose: W[j][k] -> Wt[k][j] ----------------
__global__ __launch_bounds__(256) void transpose_weights_kernel(
    const float* __restrict__ Wroot0, const float* __restrict__ Wrel0,
    const float* __restrict__ WrootR, const float* __restrict__ WrelR,
    const float* __restrict__ Wr1, float* __restrict__ wt)
{
  int gid = blockIdx.x * 256 + threadIdx.x;
  float v;
  if (gid < 8192) {
    int j = gid & 127, k = gid >> 7;
    v = Wroot0[j * 64 + k];
  } else if (gid < 16384) {
    int m = gid - 8192;
    int j = m & 127, k = m >> 7;
    v = Wrel0[j * 64 + k];
  } else if (gid < 65536) {
    int m = gid - 16384;
    int l = m >> 14, mm = m & 16383;
    int j = mm & 127, k = mm >> 7;
    v = WrootR[l * 16384 + j * 128 + k];
  } else if (gid < 114688) {
    int m = gid - 65536;
    int l = m >> 14, mm = m & 16383;
    int j = mm & 127, k = mm >> 7;
    v = WrelR[l * 16384 + j * 128 + k];
  } else {
    int m = gid - 114688;
    int j = m & 63, k = m >> 6;
    v = Wr1[j * 128 + k];
  }
  wt[gid] = v;
}

// ---------------- CSR build ----------------
__global__ __launch_bounds__(256) void hist_kernel(
    const int* __restrict__ ei, int* __restrict__ deg)
{
  int e = blockIdx.x * 256 + threadIdx.x;
  if (e < NEDGES) atomicAdd(&deg[ei[NEDGES + e]], 1);
}

__global__ __launch_bounds__(256) void scan1_kernel(
    const int* __restrict__ deg, int* __restrict__ exloc, int* __restrict__ bsum)
{
  __shared__ int s[256];
  int i = blockIdx.x * 256 + threadIdx.x;
  int v = (i < NNODES) ? deg[i] : 0;
  s[threadIdx.x] = v;
  __syncthreads();
#pragma unroll
  for (int off = 1; off < 256; off <<= 1) {
    int t = (threadIdx.x >= off) ? s[threadIdx.x - off] : 0;
    __syncthreads();
    s[threadIdx.x] += t;
    __syncthreads();
  }
  if (i < NNODES) exloc[i] = s[threadIdx.x] - v;   // exclusive within block
  if (threadIdx.x == 255) bsum[blockIdx.x] = s[255];
}

__global__ __launch_bounds__(512) void scan2_kernel(int* __restrict__ bsum)
{
  __shared__ int s[512];
  int v = (threadIdx.x < NB_SCAN) ? bsum[threadIdx.x] : 0;
  s[threadIdx.x] = v;
  __syncthreads();
#pragma unroll
  for (int off = 1; off < 512; off <<= 1) {
    int t = (threadIdx.x >= off) ? s[threadIdx.x - off] : 0;
    __syncthreads();
    s[threadIdx.x] += t;
    __syncthreads();
  }
  if (threadIdx.x < NB_SCAN) bsum[threadIdx.x] = s[threadIdx.x] - v;  // exclusive
}

__global__ __launch_bounds__(256) void scan3_kernel(
    const int* __restrict__ exloc, const int* __restrict__ bsum,
    int* __restrict__ row_ptr, int* __restrict__ row_fill)
{
  int i = blockIdx.x * 256 + threadIdx.x;
  if (i < NNODES) {
    int v = exloc[i] + bsum[blockIdx.x];
    row_ptr[i] = v;
    row_fill[i] = v;
  }
  if (i == 0) row_ptr[NNODES] = NEDGES;
}

__global__ __launch_bounds__(256) void fill_kernel(
    const int* __restrict__ ei, const float* __restrict__ ew,
    int* __restrict__ row_fill, int* __restrict__ srcs, float* __restrict__ wgt)
{
  int e = blockIdx.x * 256 + threadIdx.x;
  if (e < NEDGES) {
    int d = ei[NEDGES + e];
    int p = atomicAdd(&row_fill[d], 1);
    srcs[p] = ei[e];
    wgt[p] = ew[e];
  }
}

// ---------------- graph pointer build (batch is sorted) ----------------
__global__ __launch_bounds__(256) void gptr_kernel(
    const int* __restrict__ batch, int* __restrict__ gptr)
{
  int i = blockIdx.x * 256 + threadIdx.x;
  if (i >= NNODES) return;
  int b = batch[i];
  int bn = (i + 1 < NNODES) ? batch[i + 1] : NGRAPH;
  for (int g = b + 1; g <= bn; g++) gptr[g] = i + 1;
  if (i == 0) {
    for (int g = 0; g <= b; g++) gptr[g] = 0;
  }
}

// ---------------- gather aggregation (atomic-free) ----------------
__global__ __launch_bounds__(256) void agg128_kernel(
    const int* __restrict__ row_ptr, const int* __restrict__ srcs,
    const float* __restrict__ wgt, const float* __restrict__ x,
    float* __restrict__ agg)
{
  int node = blockIdx.x * 4 + (threadIdx.x >> 6);
  int lane = threadIdx.x & 63;
  if (node >= NNODES) return;
  int i = row_ptr[node], end = row_ptr[node + 1];
  float2 acc = make_float2(0.f, 0.f);
  for (; i + 1 < end; i += 2) {
    int sa = srcs[i], sb = srcs[i + 1];
    float wa = wgt[i], wb = wgt[i + 1];
    float2 va = *(const float2*)(x + (size_t)sa * 128 + lane * 2);
    float2 vb = *(const float2*)(x + (size_t)sb * 128 + lane * 2);
    acc.x += wa * va.x + wb * vb.x;
    acc.y += wa * va.y + wb * vb.y;
  }
  if (i < end) {
    int sa = srcs[i];
    float wa = wgt[i];
    float2 va = *(const float2*)(x + (size_t)sa * 128 + lane * 2);
    acc.x += wa * va.x;
    acc.y += wa * va.y;
  }
  *(float2*)(agg + (size_t)node * 128 + lane * 2) = acc;
}

__global__ __launch_bounds__(256) void agg64_kernel(
    const int* __restrict__ row_ptr, const int* __restrict__ srcs,
    const float* __restrict__ wgt, const float* __restrict__ x,
    float* __restrict__ agg)
{
  int node = blockIdx.x * 4 + (threadIdx.x >> 6);
  int lane = threadIdx.x & 63;
  if (node >= NNODES) return;
  int i = row_ptr[node], end = row_ptr[node + 1];
  float acc = 0.f;
  for (; i + 1 < end; i += 2) {
    int sa = srcs[i], sb = srcs[i + 1];
    float wa = wgt[i], wb = wgt[i + 1];
    float va = x[(size_t)sa * 64 + lane];
    float vb = x[(size_t)sb * 64 + lane];
    acc += wa * va + wb * vb;
  }
  if (i < end) acc += wgt[i] * x[(size_t)srcs[i] * 64 + lane];
  agg[(size_t)node * 64 + lane] = acc;
}

// ---------------- tiled fp32 GEMM ----------------
__device__ inline void fma_acc4(float (&acc)[4], const float4 av,
                                const float4 w0, const float4 w1,
                                const float4 w2, const float4 w3)
{
  acc[0] += av.x * w0.x + av.y * w1.x + av.z * w2.x + av.w * w3.x;
  acc[1] += av.x * w0.y + av.y * w1.y + av.z * w2.y + av.w * w3.y;
  acc[2] += av.x * w0.z + av.y * w1.z + av.z * w2.z + av.w * w3.z;
  acc[3] += av.x * w0.w + av.y * w1.w + av.z * w2.w + av.w * w3.w;
}

template <int KDIM, int HOUT, bool DUAL, bool RELU>
__global__ __launch_bounds__(256) void gemm_kernel(
    const float* __restrict__ A, const float* __restrict__ WtA,
    const float* __restrict__ B, const float* __restrict__ WtB,
    const float* __restrict__ bias, float* __restrict__ out)
{
  constexpr int KC = 32;
  constexpr int SAP = KC + 4;
  constexpr int JT = HOUT / 4;
  constexpr int NG = 256 / JT;
  constexpr int NT = NG * 4;

  __shared__ float sWa[KC * HOUT];
  __shared__ float sWb[DUAL ? KC * HOUT : 4];
  __shared__ float sA[NT * SAP];
  __shared__ float sB[DUAL ? NT * SAP : 4];

  const int tid = threadIdx.x;
  const int jt = tid % JT, j0 = jt * 4;
  const int ng = tid / JT, n0 = ng * 4;
  const int nbase = blockIdx.x * NT;

  float acc[4][4];
#pragma unroll
  for (int a = 0; a < 4; a++)
#pragma unroll
    for (int b = 0; b < 4; b++) acc[a][b] = 0.f;

  for (int k0 = 0; k0 < KDIM; k0 += KC) {
    {
      constexpr int WV = KC * HOUT / 4;
      const float4* ga = (const float4*)(WtA + (size_t)k0 * HOUT);
      float4* la = (float4*)sWa;
#pragma unroll
      for (int t = 0; t < WV / 256; t++) la[tid + t * 256] = ga[tid + t * 256];
      if (DUAL) {
        const float4* gb = (const float4*)(WtB + (size_t)k0 * HOUT);
        float4* lb = (float4*)sWb;
#pragma unroll
        for (int t = 0; t < WV / 256; t++) lb[tid + t * 256] = gb[tid + t * 256];
      }
    }
    {
      constexpr int AV = NT * KC / 4;
#pragma unroll
      for (int t = 0; t < AV / 256; t++) {
        int id = tid + t * 256;
        int n = id / (KC / 4);
        int kk4 = (id % (KC / 4)) * 4;
        int gn = nbase + n;
        float4 va = make_float4(0.f, 0.f, 0.f, 0.f);
        if (gn < NNODES) va = *(const float4*)(A + (size_t)gn * KDIM + k0 + kk4);
        *(float4*)(sA + n * SAP + kk4) = va;
        if (DUAL) {
          float4 vb = make_float4(0.f, 0.f, 0.f, 0.f);
          if (gn < NNODES) vb = *(const float4*)(B + (size_t)gn * KDIM + k0 + kk4);
          *(float4*)(sB + n * SAP + kk4) = vb;
        }
      }
    }
    __syncthreads();

#pragma unroll
    for (int kk = 0; kk < KC; kk += 4) {
      float4 wa0 = *(const float4*)(sWa + (kk + 0) * HOUT + j0);
      float4 wa1 = *(const float4*)(sWa + (kk + 1) * HOUT + j0);
      float4 wa2 = *(const float4*)(sWa + (kk + 2) * HOUT + j0);
      float4 wa3 = *(const float4*)(sWa + (kk + 3) * HOUT + j0);
      float4 wb0, wb1, wb2, wb3;
      if (DUAL) {
        wb0 = *(const float4*)(sWb + (kk + 0) * HOUT + j0);
        wb1 = *(const float4*)(sWb + (kk + 1) * HOUT + j0);
        wb2 = *(const float4*)(sWb + (kk + 2) * HOUT + j0);
        wb3 = *(const float4*)(sWb + (kk + 3) * HOUT + j0);
      }
#pragma unroll
      for (int nn = 0; nn < 4; nn++) {
        float4 av = *(const float4*)(sA + (n0 + nn) * SAP + kk);
        fma_acc4(acc[nn], av, wa0, wa1, wa2, wa3);
        if (DUAL) {
          float4 bv = *(const float4*)(sB + (n0 + nn) * SAP + kk);
          fma_acc4(acc[nn], bv, wb0, wb1, wb2, wb3);
        }
      }
    }
    __syncthreads();
  }

  float4 bs = *(const float4*)(bias + j0);
#pragma unroll
  for (int nn = 0; nn < 4; nn++) {
    int gn = nbase + n0 + nn;
    if (gn < NNODES) {
      float4 r;
      r.x = acc[nn][0] + bs.x;
      r.y = acc[nn][1] + bs.y;
      r.z = acc[nn][2] + bs.z;
      r.w = acc[nn][3] + bs.w;
      if (RELU) {
        r.x = fmaxf(r.x, 0.f); r.y = fmaxf(r.y, 0.f);
        r.z = fmaxf(r.z, 0.f); r.w = fmaxf(r.w, 0.f);
      }
      *(float4*)(out + (size_t)gn * HOUT + j0) = r;
    }
  }
}

// ---------------- readout: per-graph block reduction (no atomics) ----------------
__global__ __launch_bounds__(256) void readout_reduce_kernel(
    const float* __restrict__ h, const float* __restrict__ Wr2,
    const float* __restrict__ br2, const int* __restrict__ gptr,
    float* __restrict__ out)
{
  __shared__ float wsum[4];
  int g = blockIdx.x;
  int s = gptr[g], e = gptr[g + 1];
  int wave = threadIdx.x >> 6, lane = threadIdx.x & 63;
  float w2 = Wr2[lane];
  float acc = 0.f;
  for (int n = s + wave; n < e; n += 4)
    acc += h[(size_t)n * 64 + lane] * w2;
#pragma unroll
  for (int off = 32; off >= 1; off >>= 1) acc += __shfl_xor(acc, off, 64);
  if (lane == 0) wsum[wave] = acc;
  __syncthreads();
  if (threadIdx.x == 0) {
    float cnt = (float)(e - s);
    float sum = wsum[0] + wsum[1] + wsum[2] + wsum[3] + cnt * br2[0];
    out[g] = sum / fmaxf(cnt, 1.f);
  }
}

// ---------------- launch ----------------
extern "C" void kernel_launch(void* const* d_in, const int* in_sizes, int n_in,
                              void* d_out, int out_size, void* d_ws, size_t ws_size,
                              hipStream_t stream)
{
  const float* x      = (const float*)d_in[0];
  const int*   ei     = (const int*)d_in[1];
  const float* ew     = (const float*)d_in[2];
  const int*   batch  = (const int*)d_in[3];
  const float* Wroot0 = (const float*)d_in[4];
  const float* Wrel0  = (const float*)d_in[5];
  const float* b0     = (const float*)d_in[6];
  const float* WrootR = (const float*)d_in[7];
  const float* WrelR  = (const float*)d_in[8];
  const float* bR     = (const float*)d_in[9];
  const float* Wr1    = (const float*)d_in[10];
  const float* br1    = (const float*)d_in[11];
  const float* Wr2    = (const float*)d_in[12];
  const float* br2    = (const float*)d_in[13];

  char* ws = (char*)d_ws;
  float* wt   = (float*)ws;                          // 122880 floats, pad to 131072
  float* bufA = wt + 131072;                         // N*128 f32 = 51.2MB
  float* bufB = bufA + (size_t)NNODES * HID;         // N*128 f32 = 51.2MB
  int*   deg      = (int*)(bufB + (size_t)NNODES * HID);  // N
  int*   exloc    = deg + NNODES;                    // N
  int*   row_ptr  = exloc + NNODES;                  // N+1
  int*   row_fill = row_ptr + NNODES + 2;            // N
  int*   bsum     = row_fill + NNODES;               // 512
  int*   gptr     = bsum + 512;                      // G+1
  int*   srcs     = gptr + NGRAPH + 2;               // E
  float* wgt      = (float*)(srcs + NEDGES);         // E

  transpose_weights_kernel<<<480, 256, 0, stream>>>(Wroot0, Wrel0, WrootR, WrelR, Wr1, wt);
  const float* wtRoot0 = wt;
  const float* wtRel0  = wt + 8192;
  const float* wtRootR = wt + 16384;
  const float* wtRelR  = wt + 65536;
  const float* wtR1    = wt + 114688;

  // ---- CSR build (by dst) + graph ptr ----
  hipMemsetAsync(deg, 0, NNODES * sizeof(int), stream);
  hist_kernel<<<(NEDGES + 255) / 256, 256, 0, stream>>>(ei, deg);
  scan1_kernel<<<NB_SCAN, 256, 0, stream>>>(deg, exloc, bsum);
  scan2_kernel<<<1, 512, 0, stream>>>(bsum);
  scan3_kernel<<<NB_SCAN, 256, 0, stream>>>(exloc, bsum, row_ptr, row_fill);
  fill_kernel<<<(NEDGES + 255) / 256, 256, 0, stream>>>(ei, ew, row_fill, srcs, wgt);
  gptr_kernel<<<(NNODES + 255) / 256, 256, 0, stream>>>(batch, gptr);

  // ---- layer 0: IN=64 -> H=128 ----
  agg64_kernel<<<(NNODES + 3) / 4, 256, 0, stream>>>(row_ptr, srcs, wgt, x, bufA);
  gemm_kernel<64, 128, true, false><<<(NNODES + 31) / 32, 256, 0, stream>>>(
      bufA, wtRel0, x, wtRoot0, b0, bufB);

  // ---- layers 1..3: H -> H ----
  float* bufs[2] = { bufB, bufA };
  for (int l = 0; l < 3; l++) {
    float* in  = bufs[l & 1];
    float* agg = bufs[(l & 1) ^ 1];
    agg128_kernel<<<(NNODES + 3) / 4, 256, 0, stream>>>(row_ptr, srcs, wgt, in, agg);
    gemm_kernel<128, 128, true, false><<<(NNODES + 31) / 32, 256, 0, stream>>>(
        agg, wtRelR + l * 16384, in, wtRootR + l * 16384, bR + l * 128, agg);
  }
  // y3 in bufA

  // ---- readout ----
  gemm_kernel<128, 64, false, true><<<(NNODES + 63) / 64, 256, 0, stream>>>(
      bufA, wtR1, nullptr, nullptr, br1, bufB);
  readout_reduce_kernel<<<NGRAPH, 256, 0, stream>>>(bufB, Wr2, br2, gptr, (float*)d_out);
}

// Round 4
// 803.263 us; speedup vs baseline: 12.6786x; 1.5031x over previous
//
#include <hip/hip_runtime.h>
#include <cstdint>
#include <cstddef>

#define NNODES 100000
#define NEDGES 1600000
#define NGRAPH 1024
#define NB_SCAN ((NNODES + 255) / 256)   // 391

typedef __attribute__((ext_vector_type(8))) short short8;
typedef __attribute__((ext_vector_type(4))) float f32x4;

__device__ inline float b2f(unsigned short u) {
  return __uint_as_float(((unsigned int)u) << 16);
}
__device__ inline unsigned short f2b(float f) {
  unsigned int x = __float_as_uint(f);
  x += 0x7fffu + ((x >> 16) & 1u);          // RNE
  return (unsigned short)(x >> 16);
}

// ---------------- weight prepack: W[HOUT][K] f32 -> bf16 MFMA-B order ----------------
// packed[(k8*HOUT + n)*8 + j] = bf16(W[n][k8*8+j])   (k8 = k/8)
// ushort offsets in pool: Wrel0@0(8192) Wroot0@8192 WrelR@16384+l*16384 WrootR@65536+l*16384 Wr1@114688
__global__ __launch_bounds__(256) void prepack_kernel(
    const float* __restrict__ Wrel0, const float* __restrict__ Wroot0,
    const float* __restrict__ WrelR, const float* __restrict__ WrootR,
    const float* __restrict__ Wr1, unsigned short* __restrict__ dst)
{
  int g = blockIdx.x * 256 + threadIdx.x;
  if (g >= 15360) return;
  const float* src; int H, K, r; unsigned short* out;
  if (g < 1024)       { src = Wrel0;  H = 128; K = 64;  r = g;        out = dst + r * 8; }
  else if (g < 2048)  { src = Wroot0; H = 128; K = 64;  r = g - 1024; out = dst + 8192 + r * 8; }
  else if (g < 8192)  { int m = g - 2048; int l = m / 2048; r = m % 2048;
                        src = WrelR + l * 16384;  H = 128; K = 128;
                        out = dst + 16384 + l * 16384 + r * 8; }
  else if (g < 14336) { int m = g - 8192; int l = m / 2048; r = m % 2048;
                        src = WrootR + l * 16384; H = 128; K = 128;
                        out = dst + 65536 + l * 16384 + r * 8; }
  else                { src = Wr1;    H = 64;  K = 128; r = g - 14336; out = dst + 114688 + r * 8; }
  int n = r % H, k8 = r / H;
  const float* s = src + (size_t)n * K + k8 * 8;
#pragma unroll
  for (int j = 0; j < 8; j++) out[j] = f2b(s[j]);
}

// ---------------- x f32 -> bf16 ----------------
__global__ __launch_bounds__(256) void cvt_x_kernel(
    const float* __restrict__ x, unsigned short* __restrict__ xb)
{
  int i = blockIdx.x * 256 + threadIdx.x;   // group of 4
  if (i * 4 >= NNODES * 64) return;
  float4 v = *(const float4*)(x + i * 4);
  ushort4 o;
  o.x = f2b(v.x); o.y = f2b(v.y); o.z = f2b(v.z); o.w = f2b(v.w);
  *(ushort4*)(xb + i * 4) = o;
}

// ---------------- CSR build ----------------
__global__ __launch_bounds__(256) void hist_kernel(
    const int* __restrict__ ei, int* __restrict__ deg)
{
  int e = blockIdx.x * 256 + threadIdx.x;
  if (e < NEDGES) atomicAdd(&deg[ei[NEDGES + e]], 1);
}

__global__ __launch_bounds__(256) void scan1_kernel(
    const int* __restrict__ deg, int* __restrict__ exloc, int* __restrict__ bsum)
{
  __shared__ int s[256];
  int i = blockIdx.x * 256 + threadIdx.x;
  int v = (i < NNODES) ? deg[i] : 0;
  s[threadIdx.x] = v;
  __syncthreads();
#pragma unroll
  for (int off = 1; off < 256; off <<= 1) {
    int t = (threadIdx.x >= off) ? s[threadIdx.x - off] : 0;
    __syncthreads();
    s[threadIdx.x] += t;
    __syncthreads();
  }
  if (i < NNODES) exloc[i] = s[threadIdx.x] - v;
  if (threadIdx.x == 255) bsum[blockIdx.x] = s[255];
}

__global__ __launch_bounds__(512) void scan2_kernel(int* __restrict__ bsum)
{
  __shared__ int s[512];
  int v = (threadIdx.x < NB_SCAN) ? bsum[threadIdx.x] : 0;
  s[threadIdx.x] = v;
  __syncthreads();
#pragma unroll
  for (int off = 1; off < 512; off <<= 1) {
    int t = (threadIdx.x >= off) ? s[threadIdx.x - off] : 0;
    __syncthreads();
    s[threadIdx.x] += t;
    __syncthreads();
  }
  if (threadIdx.x < NB_SCAN) bsum[threadIdx.x] = s[threadIdx.x] - v;
}

__global__ __launch_bounds__(256) void scan3_kernel(
    const int* __restrict__ exloc, const int* __restrict__ bsum,
    int* __restrict__ row_ptr, int* __restrict__ row_fill)
{
  int i = blockIdx.x * 256 + threadIdx.x;
  if (i < NNODES) {
    int v = exloc[i] + bsum[blockIdx.x];
    row_ptr[i] = v;
    row_fill[i] = v;
  }
  if (i == 0) row_ptr[NNODES] = NEDGES;
}

__global__ __launch_bounds__(256) void fill_kernel(
    const int* __restrict__ ei, const float* __restrict__ ew,
    int* __restrict__ row_fill, int2* __restrict__ edges)
{
  int e = blockIdx.x * 256 + threadIdx.x;
  if (e < NEDGES) {
    int d = ei[NEDGES + e];
    int p = atomicAdd(&row_fill[d], 1);
    edges[p] = make_int2(ei[e], __float_as_int(ew[e]));
  }
}

// ---------------- graph pointer (batch sorted) ----------------
__global__ __launch_bounds__(256) void gptr_kernel(
    const int* __restrict__ batch, int* __restrict__ gptr)
{
  int i = blockIdx.x * 256 + threadIdx.x;
  if (i >= NNODES) return;
  int b = batch[i];
  int bn = (i + 1 < NNODES) ? batch[i + 1] : NGRAPH;
  for (int g = b + 1; g <= bn; g++) gptr[g] = i + 1;
  if (i == 0) for (int g = 0; g <= b; g++) gptr[g] = 0;
}

// ---------------- bf16 gather aggregation ----------------
// wave per node; lane halves process alternate edges; fp32 accumulate.
__global__ __launch_bounds__(256) void agg128_kernel(
    const int* __restrict__ row_ptr, const int2* __restrict__ edges,
    const unsigned short* __restrict__ x, unsigned short* __restrict__ agg)
{
  int node = blockIdx.x * 4 + (threadIdx.x >> 6);
  int lane = threadIdx.x & 63;
  if (node >= NNODES) return;
  int half = lane >> 5, cl = lane & 31;
  int s = row_ptr[node], e = row_ptr[node + 1];
  float a0 = 0.f, a1 = 0.f, a2 = 0.f, a3 = 0.f;
  for (int i = s; i + half < e; i += 2) {
    int2 ed = edges[i + half];
    float w = __int_as_float(ed.y);
    ushort4 v = *(const ushort4*)(x + (size_t)ed.x * 128 + cl * 4);
    a0 += w * b2f(v.x); a1 += w * b2f(v.y);
    a2 += w * b2f(v.z); a3 += w * b2f(v.w);
  }
  a0 += __shfl_xor(a0, 32, 64);
  a1 += __shfl_xor(a1, 32, 64);
  a2 += __shfl_xor(a2, 32, 64);
  a3 += __shfl_xor(a3, 32, 64);
  if (half == 0) {
    ushort4 o;
    o.x = f2b(a0); o.y = f2b(a1); o.z = f2b(a2); o.w = f2b(a3);
    *(ushort4*)(agg + (size_t)node * 128 + cl * 4) = o;
  }
}

__global__ __launch_bounds__(256) void agg64_kernel(
    const int* __restrict__ row_ptr, const int2* __restrict__ edges,
    const unsigned short* __restrict__ x, unsigned short* __restrict__ agg)
{
  int node = blockIdx.x * 4 + (threadIdx.x >> 6);
  int lane = threadIdx.x & 63;
  if (node >= NNODES) return;
  int half = lane >> 5, cl = lane & 31;
  int s = row_ptr[node], e = row_ptr[node + 1];
  float a0 = 0.f, a1 = 0.f;
  for (int i = s; i + half < e; i += 2) {
    int2 ed = edges[i + half];
    float w = __int_as_float(ed.y);
    ushort2 v = *(const ushort2*)(x + (size_t)ed.x * 64 + cl * 2);
    a0 += w * b2f(v.x); a1 += w * b2f(v.y);
  }
  a0 += __shfl_xor(a0, 32, 64);
  a1 += __shfl_xor(a1, 32, 64);
  if (half == 0) {
    ushort2 o; o.x = f2b(a0); o.y = f2b(a1);
    *(ushort2*)(agg + (size_t)node * 64 + cl * 2) = o;
  }
}

// ---------------- LDS-free MFMA bf16 GEMM ----------------
// out[n][j] = bias[j] + sum_k A1[n][k]*W1[k][j] (+ A2/W2), optional relu, bf16 out.
// W packed B-operand order: Wp[(k8*HOUT + n)*8 + j] = W[k8*8+j][n].
// A-frag (16x16x32): lane holds A[m=lane&15][k = (lane>>4)*8 + 0..7].
// B-frag: lane holds B[k=(lane>>4)*8 + 0..7][n=lane&15].
// C/D: lane holds D[(lane>>4)*4 + r][lane&15], r=0..3.
template <int KDIM, int HOUT, int MT, bool DUAL, bool RELU>
__global__ __launch_bounds__(256) void mfma_gemm(
    const unsigned short* __restrict__ A1, const unsigned short* __restrict__ W1,
    const unsigned short* __restrict__ A2, const unsigned short* __restrict__ W2,
    const float* __restrict__ bias, unsigned short* __restrict__ out)
{
  constexpr int NT2 = HOUT / 16;
  constexpr int KC = KDIM / 32;
  const int wave = threadIdx.x >> 6, lane = threadIdx.x & 63;
  const int quad = lane >> 4, l16 = lane & 15;
  const int n0 = (blockIdx.x * 4 + wave) * (MT * 16);

  f32x4 acc[MT][NT2];
#pragma unroll
  for (int m = 0; m < MT; m++)
#pragma unroll
    for (int t = 0; t < NT2; t++) acc[m][t] = (f32x4){0.f, 0.f, 0.f, 0.f};

  int nodes[MT];
#pragma unroll
  for (int m = 0; m < MT; m++) {
    int nd = n0 + m * 16 + l16;
    nodes[m] = nd < NNODES ? nd : NNODES - 1;   // clamp; garbage rows never stored
  }

#pragma unroll
  for (int c = 0; c < KC; c++) {
    short8 bfr[NT2];
#pragma unroll
    for (int t = 0; t < NT2; t++)
      bfr[t] = *(const short8*)(W1 + ((size_t)(c * 4 + quad) * HOUT + t * 16 + l16) * 8);
#pragma unroll
    for (int m = 0; m < MT; m++) {
      short8 af = *(const short8*)(A1 + (size_t)nodes[m] * KDIM + c * 32 + quad * 8);
#pragma unroll
      for (int t = 0; t < NT2; t++)
        acc[m][t] = __builtin_amdgcn_mfma_f32_16x16x32_bf16(af, bfr[t], acc[m][t], 0, 0, 0);
    }
    if (DUAL) {
#pragma unroll
      for (int t = 0; t < NT2; t++)
        bfr[t] = *(const short8*)(W2 + ((size_t)(c * 4 + quad) * HOUT + t * 16 + l16) * 8);
#pragma unroll
      for (int m = 0; m < MT; m++) {
        short8 af = *(const short8*)(A2 + (size_t)nodes[m] * KDIM + c * 32 + quad * 8);
#pragma unroll
        for (int t = 0; t < NT2; t++)
          acc[m][t] = __builtin_amdgcn_mfma_f32_16x16x32_bf16(af, bfr[t], acc[m][t], 0, 0, 0);
      }
    }
  }

#pragma unroll
  for (int m = 0; m < MT; m++) {
    int rowbase = n0 + m * 16 + quad * 4;
#pragma unroll
    for (int t = 0; t < NT2; t++) {
      float b = bias[t * 16 + l16];
#pragma unroll
      for (int r = 0; r < 4; r++) {
        int nd = rowbase + r;
        if (nd < NNODES) {
          float v = acc[m][t][r] + b;
          if (RELU) v = fmaxf(v, 0.f);
          out[(size_t)nd * HOUT + t * 16 + l16] = f2b(v);
        }
      }
    }
  }
}

// ---------------- readout: per-graph block reduction ----------------
__global__ __launch_bounds__(256) void readout_reduce_kernel(
    const unsigned short* __restrict__ h, const float* __restrict__ Wr2,
    const float* __restrict__ br2, const int* __restrict__ gptr,
    float* __restrict__ out)
{
  __shared__ float wsum[4];
  int g = blockIdx.x;
  int s = gptr[g], e = gptr[g + 1];
  int wave = threadIdx.x >> 6, lane = threadIdx.x & 63;
  float w2 = Wr2[lane];
  float acc = 0.f;
  for (int n = s + wave; n < e; n += 4)
    acc += b2f(h[(size_t)n * 64 + lane]) * w2;
#pragma unroll
  for (int off = 32; off >= 1; off >>= 1) acc += __shfl_xor(acc, off, 64);
  if (lane == 0) wsum[wave] = acc;
  __syncthreads();
  if (threadIdx.x == 0) {
    float cnt = (float)(e - s);
    float sum = wsum[0] + wsum[1] + wsum[2] + wsum[3] + cnt * br2[0];
    out[g] = sum / fmaxf(cnt, 1.f);
  }
}

// ---------------- launch ----------------
extern "C" void kernel_launch(void* const* d_in, const int* in_sizes, int n_in,
                              void* d_out, int out_size, void* d_ws, size_t ws_size,
                              hipStream_t stream)
{
  const float* x      = (const float*)d_in[0];
  const int*   ei     = (const int*)d_in[1];
  const float* ew     = (const float*)d_in[2];
  const int*   batch  = (const int*)d_in[3];
  const float* Wroot0 = (const float*)d_in[4];
  const float* Wrel0  = (const float*)d_in[5];
  const float* b0     = (const float*)d_in[6];
  const float* WrootR = (const float*)d_in[7];
  const float* WrelR  = (const float*)d_in[8];
  const float* bR     = (const float*)d_in[9];
  const float* Wr1    = (const float*)d_in[10];
  const float* br1    = (const float*)d_in[11];
  const float* Wr2    = (const float*)d_in[12];
  const float* br2    = (const float*)d_in[13];

  char* ws = (char*)d_ws;
  unsigned short* wp   = (unsigned short*)ws;                 // 122880 bf16, pad to 131072
  unsigned short* xb   = wp + 131072;                         // N*64 bf16 = 12.8MB
  unsigned short* agg0 = xb + (size_t)NNODES * 64;            // N*64 bf16
  unsigned short* bufA = agg0 + (size_t)NNODES * 64;          // N*128 bf16 = 25.6MB
  unsigned short* bufB = bufA + (size_t)NNODES * 128;         // N*128 bf16
  unsigned short* hbuf = bufB + (size_t)NNODES * 128;         // N*64 bf16
  int*  deg      = (int*)(hbuf + (size_t)NNODES * 64);
  int*  exloc    = deg + NNODES;
  int*  row_ptr  = exloc + NNODES;
  int*  row_fill = row_ptr + NNODES + 2;
  int*  bsum     = row_fill + NNODES;
  int*  gptr     = bsum + 512;
  int2* edges    = (int2*)(gptr + NGRAPH + 2);                // E int2 = 12.8MB

  prepack_kernel<<<60, 256, 0, stream>>>(Wrel0, Wroot0, WrelR, WrootR, Wr1, wp);
  cvt_x_kernel<<<(NNODES * 64 / 4 + 255) / 256, 256, 0, stream>>>(x, xb);

  const unsigned short* pWrel0  = wp;
  const unsigned short* pWroot0 = wp + 8192;
  const unsigned short* pWrelR  = wp + 16384;
  const unsigned short* pWrootR = wp + 65536;
  const unsigned short* pWr1    = wp + 114688;

  // CSR (by dst) + graph ptr
  hipMemsetAsync(deg, 0, NNODES * sizeof(int), stream);
  hist_kernel<<<(NEDGES + 255) / 256, 256, 0, stream>>>(ei, deg);
  scan1_kernel<<<NB_SCAN, 256, 0, stream>>>(deg, exloc, bsum);
  scan2_kernel<<<1, 512, 0, stream>>>(bsum);
  scan3_kernel<<<NB_SCAN, 256, 0, stream>>>(exloc, bsum, row_ptr, row_fill);
  fill_kernel<<<(NEDGES + 255) / 256, 256, 0, stream>>>(ei, ew, row_fill, edges);
  gptr_kernel<<<(NNODES + 255) / 256, 256, 0, stream>>>(batch, gptr);

  // layer 0: 64 -> 128
  agg64_kernel<<<(NNODES + 3) / 4, 256, 0, stream>>>(row_ptr, edges, xb, agg0);
  mfma_gemm<64, 128, 2, true, false><<<(NNODES + 127) / 128, 256, 0, stream>>>(
      agg0, pWrel0, xb, pWroot0, b0, bufB);

  // layers 1..3: 128 -> 128 (in-place GEMM over agg buffer)
  unsigned short* bufs[2] = { bufB, bufA };
  for (int l = 0; l < 3; l++) {
    unsigned short* in  = bufs[l & 1];
    unsigned short* agg = bufs[(l & 1) ^ 1];
    agg128_kernel<<<(NNODES + 3) / 4, 256, 0, stream>>>(row_ptr, edges, in, agg);
    mfma_gemm<128, 128, 2, true, false><<<(NNODES + 127) / 128, 256, 0, stream>>>(
        agg, pWrelR + l * 16384, in, pWrootR + l * 16384, bR + l * 128, agg);
  }
  // y3 in bufA

  // readout
  mfma_gemm<128, 64, 4, false, true><<<(NNODES + 255) / 256, 256, 0, stream>>>(
      bufA, pWr1, nullptr, nullptr, br1, hbuf);
  readout_reduce_kernel<<<NGRAPH, 256, 0, stream>>>(hbuf, Wr2, br2, gptr, (float*)d_out);
}

// Round 5
// 651.003 us; speedup vs baseline: 15.6439x; 1.2339x over previous
//
#include <hip/hip_runtime.h>
#include <hip/hip_fp16.h>
#include <cstdint>
#include <cstddef>

#define NNODES 100000
#define NEDGES 1600000
#define NGRAPH 1024
#define NB_SCAN ((NNODES + 255) / 256)   // 391

typedef __attribute__((ext_vector_type(8))) short short8;
typedef __attribute__((ext_vector_type(8))) unsigned short ushort8;
typedef __attribute__((ext_vector_type(4))) float f32x4;

__device__ inline float b2f(unsigned short u) {
  return __uint_as_float(((unsigned int)u) << 16);
}
__device__ inline unsigned short f2b(float f) {
  unsigned int x = __float_as_uint(f);
  x += 0x7fffu + ((x >> 16) & 1u);          // RNE
  return (unsigned short)(x >> 16);
}
// packed edge: (src << 15) | (fp16(weight) >> 1)   [weight >= 0 so sign bit = 0]
__device__ inline unsigned int pack_edge(int src, float w) {
  unsigned short hb = __half_as_ushort(__float2half_rn(w));
  return ((unsigned int)src << 15) | ((unsigned int)hb >> 1);
}
__device__ inline void unpack_edge(unsigned int p, int& src, float& w) {
  src = (int)(p >> 15);
  w = __half2float(__ushort_as_half((unsigned short)((p & 0x7fffu) << 1)));
}

// ---------------- weight prepack: W[HOUT][K] f32 -> bf16 MFMA-B order ----------------
__global__ __launch_bounds__(256) void prepack_kernel(
    const float* __restrict__ Wrel0, const float* __restrict__ Wroot0,
    const float* __restrict__ WrelR, const float* __restrict__ WrootR,
    const float* __restrict__ Wr1, unsigned short* __restrict__ dst)
{
  int g = blockIdx.x * 256 + threadIdx.x;
  if (g >= 15360) return;
  const float* src; int H, K, r; unsigned short* out;
  if (g < 1024)       { src = Wrel0;  H = 128; K = 64;  r = g;        out = dst + r * 8; }
  else if (g < 2048)  { src = Wroot0; H = 128; K = 64;  r = g - 1024; out = dst + 8192 + r * 8; }
  else if (g < 8192)  { int m = g - 2048; int l = m / 2048; r = m % 2048;
                        src = WrelR + l * 16384;  H = 128; K = 128;
                        out = dst + 16384 + l * 16384 + r * 8; }
  else if (g < 14336) { int m = g - 8192; int l = m / 2048; r = m % 2048;
                        src = WrootR + l * 16384; H = 128; K = 128;
                        out = dst + 65536 + l * 16384 + r * 8; }
  else                { src = Wr1;    H = 64;  K = 128; r = g - 14336; out = dst + 114688 + r * 8; }
  int n = r % H, k8 = r / H;
  const float* s = src + (size_t)n * K + k8 * 8;
#pragma unroll
  for (int j = 0; j < 8; j++) out[j] = f2b(s[j]);
}

// ---------------- x f32 -> bf16 ----------------
__global__ __launch_bounds__(256) void cvt_x_kernel(
    const float* __restrict__ x, unsigned short* __restrict__ xb)
{
  int i = blockIdx.x * 256 + threadIdx.x;
  if (i * 4 >= NNODES * 64) return;
  float4 v = *(const float4*)(x + i * 4);
  ushort4 o;
  o.x = f2b(v.x); o.y = f2b(v.y); o.z = f2b(v.z); o.w = f2b(v.w);
  *(ushort4*)(xb + i * 4) = o;
}

// ---------------- CSR build ----------------
__global__ __launch_bounds__(256) void hist_kernel(
    const int* __restrict__ ei, int* __restrict__ deg)
{
  int e = blockIdx.x * 256 + threadIdx.x;
  if (e < NEDGES) atomicAdd(&deg[ei[NEDGES + e]], 1);
}

__global__ __launch_bounds__(256) void scan1_kernel(
    const int* __restrict__ deg, int* __restrict__ exloc, int* __restrict__ bsum)
{
  __shared__ int s[256];
  int i = blockIdx.x * 256 + threadIdx.x;
  int v = (i < NNODES) ? deg[i] : 0;
  s[threadIdx.x] = v;
  __syncthreads();
#pragma unroll
  for (int off = 1; off < 256; off <<= 1) {
    int t = (threadIdx.x >= off) ? s[threadIdx.x - off] : 0;
    __syncthreads();
    s[threadIdx.x] += t;
    __syncthreads();
  }
  if (i < NNODES) exloc[i] = s[threadIdx.x] - v;
  if (threadIdx.x == 255) bsum[blockIdx.x] = s[255];
}

__global__ __launch_bounds__(512) void scan2_kernel(int* __restrict__ bsum)
{
  __shared__ int s[512];
  int v = (threadIdx.x < NB_SCAN) ? bsum[threadIdx.x] : 0;
  s[threadIdx.x] = v;
  __syncthreads();
#pragma unroll
  for (int off = 1; off < 512; off <<= 1) {
    int t = (threadIdx.x >= off) ? s[threadIdx.x - off] : 0;
    __syncthreads();
    s[threadIdx.x] += t;
    __syncthreads();
  }
  if (threadIdx.x < NB_SCAN) bsum[threadIdx.x] = s[threadIdx.x] - v;
}

__global__ __launch_bounds__(256) void scan3_kernel(
    const int* __restrict__ exloc, const int* __restrict__ bsum,
    int* __restrict__ row_ptr, int* __restrict__ row_fill)
{
  int i = blockIdx.x * 256 + threadIdx.x;
  if (i < NNODES) {
    int v = exloc[i] + bsum[blockIdx.x];
    row_ptr[i] = v;
    row_fill[i] = v;
  }
  if (i == 0) row_ptr[NNODES] = NEDGES;
}

__global__ __launch_bounds__(256) void fill_kernel(
    const int* __restrict__ ei, const float* __restrict__ ew,
    int* __restrict__ row_fill, unsigned int* __restrict__ epack)
{
  int e = blockIdx.x * 256 + threadIdx.x;
  if (e < NEDGES) {
    int d = ei[NEDGES + e];
    int p = atomicAdd(&row_fill[d], 1);
    epack[p] = pack_edge(ei[e], ew[e]);
  }
}

// ---------------- graph pointer (batch sorted) ----------------
__global__ __launch_bounds__(256) void gptr_kernel(
    const int* __restrict__ batch, int* __restrict__ gptr)
{
  int i = blockIdx.x * 256 + threadIdx.x;
  if (i >= NNODES) return;
  int b = batch[i];
  int bn = (i + 1 < NNODES) ? batch[i + 1] : NGRAPH;
  for (int g = b + 1; g <= bn; g++) gptr[g] = i + 1;
  if (i == 0) for (int g = 0; g <= b; g++) gptr[g] = 0;
}

// ---------------- bf16 gather aggregation, high-MLP ----------------
// agg128: wave per node, quarter-split (4 edges in flight) x2 unroll.
// Each quarter: 16 lanes x ushort8 (16B) = full 256B row.
__global__ __launch_bounds__(256) void agg128_kernel(
    const int* __restrict__ row_ptr, const unsigned int* __restrict__ epack,
    const unsigned short* __restrict__ x, unsigned short* __restrict__ agg)
{
  int node = blockIdx.x * 4 + (threadIdx.x >> 6);
  int lane = threadIdx.x & 63;
  if (node >= NNODES) return;
  int q = lane >> 4, sl = lane & 15;
  int s = row_ptr[node], e = row_ptr[node + 1];
  float acc[8];
#pragma unroll
  for (int j = 0; j < 8; j++) acc[j] = 0.f;

  for (int i = s + q; i < e; i += 8) {
    unsigned int pa = epack[i];
    unsigned int pb = (i + 4 < e) ? epack[i + 4] : 0u;   // src=0, w=0 neutral
    int sa, sb; float wa, wb;
    unpack_edge(pa, sa, wa);
    unpack_edge(pb, sb, wb);
    ushort8 ra = *(const ushort8*)(x + (size_t)sa * 128 + sl * 8);
    ushort8 rb = *(const ushort8*)(x + (size_t)sb * 128 + sl * 8);
#pragma unroll
    for (int j = 0; j < 8; j++)
      acc[j] += wa * b2f(ra[j]) + wb * b2f(rb[j]);
  }
#pragma unroll
  for (int j = 0; j < 8; j++) {
    acc[j] += __shfl_xor(acc[j], 16, 64);
    acc[j] += __shfl_xor(acc[j], 32, 64);
  }
  if (q == 0) {
    ushort8 o;
#pragma unroll
    for (int j = 0; j < 8; j++) o[j] = f2b(acc[j]);
    *(ushort8*)(agg + (size_t)node * 128 + sl * 8) = o;
  }
}

// agg64: wave per node, eighth-split (8 edges in flight).
// Each eighth: 8 lanes x ushort8 (16B) = full 128B row.
__global__ __launch_bounds__(256) void agg64_kernel(
    const int* __restrict__ row_ptr, const unsigned int* __restrict__ epack,
    const unsigned short* __restrict__ x, unsigned short* __restrict__ agg)
{
  int node = blockIdx.x * 4 + (threadIdx.x >> 6);
  int lane = threadIdx.x & 63;
  if (node >= NNODES) return;
  int q = lane >> 3, sl = lane & 7;
  int s = row_ptr[node], e = row_ptr[node + 1];
  float acc[8];
#pragma unroll
  for (int j = 0; j < 8; j++) acc[j] = 0.f;

  for (int i = s + q; i < e; i += 8) {
    unsigned int pa = epack[i];
    int sa; float wa;
    unpack_edge(pa, sa, wa);
    ushort8 ra = *(const ushort8*)(x + (size_t)sa * 64 + sl * 8);
#pragma unroll
    for (int j = 0; j < 8; j++) acc[j] += wa * b2f(ra[j]);
  }
#pragma unroll
  for (int j = 0; j < 8; j++) {
    acc[j] += __shfl_xor(acc[j], 8, 64);
    acc[j] += __shfl_xor(acc[j], 16, 64);
    acc[j] += __shfl_xor(acc[j], 32, 64);
  }
  if (q == 0) {
    ushort8 o;
#pragma unroll
    for (int j = 0; j < 8; j++) o[j] = f2b(acc[j]);
    *(ushort8*)(agg + (size_t)node * 64 + sl * 8) = o;
  }
}

// ---------------- LDS-free MFMA bf16 GEMM ----------------
template <int KDIM, int HOUT, int MT, bool DUAL, bool RELU>
__global__ __launch_bounds__(256) void mfma_gemm(
    const unsigned short* __restrict__ A1, const unsigned short* __restrict__ W1,
    const unsigned short* __restrict__ A2, const unsigned short* __restrict__ W2,
    const float* __restrict__ bias, unsigned short* __restrict__ out)
{
  constexpr int NT2 = HOUT / 16;
  constexpr int KC = KDIM / 32;
  const int wave = threadIdx.x >> 6, lane = threadIdx.x & 63;
  const int quad = lane >> 4, l16 = lane & 15;
  const int n0 = (blockIdx.x * 4 + wave) * (MT * 16);

  f32x4 acc[MT][NT2];
#pragma unroll
  for (int m = 0; m < MT; m++)
#pragma unroll
    for (int t = 0; t < NT2; t++) acc[m][t] = (f32x4){0.f, 0.f, 0.f, 0.f};

  int nodes[MT];
#pragma unroll
  for (int m = 0; m < MT; m++) {
    int nd = n0 + m * 16 + l16;
    nodes[m] = nd < NNODES ? nd : NNODES - 1;
  }

#pragma unroll
  for (int c = 0; c < KC; c++) {
    short8 bfr[NT2];
#pragma unroll
    for (int t = 0; t < NT2; t++)
      bfr[t] = *(const short8*)(W1 + ((size_t)(c * 4 + quad) * HOUT + t * 16 + l16) * 8);
#pragma unroll
    for (int m = 0; m < MT; m++) {
      short8 af = *(const short8*)(A1 + (size_t)nodes[m] * KDIM + c * 32 + quad * 8);
#pragma unroll
      for (int t = 0; t < NT2; t++)
        acc[m][t] = __builtin_amdgcn_mfma_f32_16x16x32_bf16(af, bfr[t], acc[m][t], 0, 0, 0);
    }
    if (DUAL) {
#pragma unroll
      for (int t = 0; t < NT2; t++)
        bfr[t] = *(const short8*)(W2 + ((size_t)(c * 4 + quad) * HOUT + t * 16 + l16) * 8);
#pragma unroll
      for (int m = 0; m < MT; m++) {
        short8 af = *(const short8*)(A2 + (size_t)nodes[m] * KDIM + c * 32 + quad * 8);
#pragma unroll
        for (int t = 0; t < NT2; t++)
          acc[m][t] = __builtin_amdgcn_mfma_f32_16x16x32_bf16(af, bfr[t], acc[m][t], 0, 0, 0);
      }
    }
  }

#pragma unroll
  for (int m = 0; m < MT; m++) {
    int rowbase = n0 + m * 16 + quad * 4;
#pragma unroll
    for (int t = 0; t < NT2; t++) {
      float b = bias[t * 16 + l16];
#pragma unroll
      for (int r = 0; r < 4; r++) {
        int nd = rowbase + r;
        if (nd < NNODES) {
          float v = acc[m][t][r] + b;
          if (RELU) v = fmaxf(v, 0.f);
          out[(size_t)nd * HOUT + t * 16 + l16] = f2b(v);
        }
      }
    }
  }
}

// ---------------- readout: per-graph block reduction ----------------
__global__ __launch_bounds__(256) void readout_reduce_kernel(
    const unsigned short* __restrict__ h, const float* __restrict__ Wr2,
    const float* __restrict__ br2, const int* __restrict__ gptr,
    float* __restrict__ out)
{
  __shared__ float wsum[4];
  int g = blockIdx.x;
  int s = gptr[g], e = gptr[g + 1];
  int wave = threadIdx.x >> 6, lane = threadIdx.x & 63;
  float w2 = Wr2[lane];
  float acc = 0.f;
  for (int n = s + wave; n < e; n += 4)
    acc += b2f(h[(size_t)n * 64 + lane]) * w2;
#pragma unroll
  for (int off = 32; off >= 1; off >>= 1) acc += __shfl_xor(acc, off, 64);
  if (lane == 0) wsum[wave] = acc;
  __syncthreads();
  if (threadIdx.x == 0) {
    float cnt = (float)(e - s);
    float sum = wsum[0] + wsum[1] + wsum[2] + wsum[3] + cnt * br2[0];
    out[g] = sum / fmaxf(cnt, 1.f);
  }
}

// ---------------- launch ----------------
extern "C" void kernel_launch(void* const* d_in, const int* in_sizes, int n_in,
                              void* d_out, int out_size, void* d_ws, size_t ws_size,
                              hipStream_t stream)
{
  const float* x      = (const float*)d_in[0];
  const int*   ei     = (const int*)d_in[1];
  const float* ew     = (const float*)d_in[2];
  const int*   batch  = (const int*)d_in[3];
  const float* Wroot0 = (const float*)d_in[4];
  const float* Wrel0  = (const float*)d_in[5];
  const float* b0     = (const float*)d_in[6];
  const float* WrootR = (const float*)d_in[7];
  const float* WrelR  = (const float*)d_in[8];
  const float* bR     = (const float*)d_in[9];
  const float* Wr1    = (const float*)d_in[10];
  const float* br1    = (const float*)d_in[11];
  const float* Wr2    = (const float*)d_in[12];
  const float* br2    = (const float*)d_in[13];

  char* ws = (char*)d_ws;
  unsigned short* wp   = (unsigned short*)ws;                 // 122880 bf16, pad to 131072
  unsigned short* xb   = wp + 131072;                         // N*64 bf16
  unsigned short* agg0 = xb + (size_t)NNODES * 64;            // N*64 bf16
  unsigned short* bufA = agg0 + (size_t)NNODES * 64;          // N*128 bf16
  unsigned short* bufB = bufA + (size_t)NNODES * 128;         // N*128 bf16
  unsigned short* hbuf = bufB + (size_t)NNODES * 128;         // N*64 bf16
  int*  deg      = (int*)(hbuf + (size_t)NNODES * 64);
  int*  exloc    = deg + NNODES;
  int*  row_ptr  = exloc + NNODES;
  int*  row_fill = row_ptr + NNODES + 2;
  int*  bsum     = row_fill + NNODES;
  int*  gptr     = bsum + 512;
  unsigned int* epack = (unsigned int*)(gptr + NGRAPH + 2);   // E uint = 6.4MB

  prepack_kernel<<<60, 256, 0, stream>>>(Wrel0, Wroot0, WrelR, WrootR, Wr1, wp);
  cvt_x_kernel<<<(NNODES * 64 / 4 + 255) / 256, 256, 0, stream>>>(x, xb);

  const unsigned short* pWrel0  = wp;
  const unsigned short* pWroot0 = wp + 8192;
  const unsigned short* pWrelR  = wp + 16384;
  const unsigned short* pWrootR = wp + 65536;
  const unsigned short* pWr1    = wp + 114688;

  // CSR (by dst) + graph ptr
  hipMemsetAsync(deg, 0, NNODES * sizeof(int), stream);
  hist_kernel<<<(NEDGES + 255) / 256, 256, 0, stream>>>(ei, deg);
  scan1_kernel<<<NB_SCAN, 256, 0, stream>>>(deg, exloc, bsum);
  scan2_kernel<<<1, 512, 0, stream>>>(bsum);
  scan3_kernel<<<NB_SCAN, 256, 0, stream>>>(exloc, bsum, row_ptr, row_fill);
  fill_kernel<<<(NEDGES + 255) / 256, 256, 0, stream>>>(ei, ew, row_fill, epack);
  gptr_kernel<<<(NNODES + 255) / 256, 256, 0, stream>>>(batch, gptr);

  // layer 0: 64 -> 128
  agg64_kernel<<<(NNODES + 3) / 4, 256, 0, stream>>>(row_ptr, epack, xb, agg0);
  mfma_gemm<64, 128, 2, true, false><<<(NNODES + 127) / 128, 256, 0, stream>>>(
      agg0, pWrel0, xb, pWroot0, b0, bufB);

  // layers 1..3: 128 -> 128
  unsigned short* bufs[2] = { bufB, bufA };
  for (int l = 0; l < 3; l++) {
    unsigned short* in  = bufs[l & 1];
    unsigned short* agg = bufs[(l & 1) ^ 1];
    agg128_kernel<<<(NNODES + 3) / 4, 256, 0, stream>>>(row_ptr, epack, in, agg);
    mfma_gemm<128, 128, 2, true, false><<<(NNODES + 127) / 128, 256, 0, stream>>>(
        agg, pWrelR + l * 16384, in, pWrootR + l * 16384, bR + l * 128, agg);
  }
  // y3 in bufA

  // readout
  mfma_gemm<128, 64, 4, false, true><<<(NNODES + 255) / 256, 256, 0, stream>>>(
      bufA, pWr1, nullptr, nullptr, br1, hbuf);
  readout_reduce_kernel<<<NGRAPH, 256, 0, stream>>>(hbuf, Wr2, br2, gptr, (float*)d_out);
}

// Round 6
// 593.289 us; speedup vs baseline: 17.1658x; 1.0973x over previous
//
#include <hip/hip_runtime.h>
#include <hip/hip_fp16.h>
#include <cstdint>
#include <cstddef>

#define NNODES 100000
#define NEDGES 1600000
#define NGRAPH 1024
#define NB_SCAN ((NNODES + 255) / 256)   // 391
#define FILL_CHUNK 4096
#define FILL_NCHUNK ((NEDGES + FILL_CHUNK - 1) / FILL_CHUNK)  // 391
#define SHARD 12500                       // NNODES / 8

typedef __attribute__((ext_vector_type(8))) short short8;
typedef __attribute__((ext_vector_type(8))) unsigned short ushort8;
typedef __attribute__((ext_vector_type(4))) float f32x4;

__device__ inline float b2f(unsigned short u) {
  return __uint_as_float(((unsigned int)u) << 16);
}
__device__ inline unsigned short f2b(float f) {
  unsigned int x = __float_as_uint(f);
  x += 0x7fffu + ((x >> 16) & 1u);          // RNE
  return (unsigned short)(x >> 16);
}
// packed edge: (src << 15) | (fp16(weight) >> 1)   [weight >= 0 so sign bit = 0]
__device__ inline unsigned int pack_edge(int src, float w) {
  unsigned short hb = __half_as_ushort(__float2half_rn(w));
  return ((unsigned int)src << 15) | ((unsigned int)hb >> 1);
}
__device__ inline void unpack_edge(unsigned int p, int& src, float& w) {
  src = (int)(p >> 15);
  w = __half2float(__ushort_as_half((unsigned short)((p & 0x7fffu) << 1)));
}

// ---------------- weight prepack: W[HOUT][K] f32 -> bf16 MFMA-B order ----------------
__global__ __launch_bounds__(256) void prepack_kernel(
    const float* __restrict__ Wrel0, const float* __restrict__ Wroot0,
    const float* __restrict__ WrelR, const float* __restrict__ WrootR,
    const float* __restrict__ Wr1, unsigned short* __restrict__ dst)
{
  int g = blockIdx.x * 256 + threadIdx.x;
  if (g >= 15360) return;
  const float* src; int H, K, r; unsigned short* out;
  if (g < 1024)       { src = Wrel0;  H = 128; K = 64;  r = g;        out = dst + r * 8; }
  else if (g < 2048)  { src = Wroot0; H = 128; K = 64;  r = g - 1024; out = dst + 8192 + r * 8; }
  else if (g < 8192)  { int m = g - 2048; int l = m / 2048; r = m % 2048;
                        src = WrelR + l * 16384;  H = 128; K = 128;
                        out = dst + 16384 + l * 16384 + r * 8; }
  else if (g < 14336) { int m = g - 8192; int l = m / 2048; r = m % 2048;
                        src = WrootR + l * 16384; H = 128; K = 128;
                        out = dst + 65536 + l * 16384 + r * 8; }
  else                { src = Wr1;    H = 64;  K = 128; r = g - 14336; out = dst + 114688 + r * 8; }
  int n = r % H, k8 = r / H;
  const float* s = src + (size_t)n * K + k8 * 8;
#pragma unroll
  for (int j = 0; j < 8; j++) out[j] = f2b(s[j]);
}

// ---------------- x f32 -> bf16 ----------------
__global__ __launch_bounds__(256) void cvt_x_kernel(
    const float* __restrict__ x, unsigned short* __restrict__ xb)
{
  int i = blockIdx.x * 256 + threadIdx.x;
  if (i * 4 >= NNODES * 64) return;
  float4 v = *(const float4*)(x + i * 4);
  ushort4 o;
  o.x = f2b(v.x); o.y = f2b(v.y); o.z = f2b(v.z); o.w = f2b(v.w);
  *(ushort4*)(xb + i * 4) = o;
}

// ---------------- CSR build ----------------
__global__ __launch_bounds__(256) void hist_kernel(
    const int* __restrict__ ei, int* __restrict__ deg)
{
  int e = blockIdx.x * 256 + threadIdx.x;
  if (e < NEDGES) atomicAdd(&deg[ei[NEDGES + e]], 1);
}

__global__ __launch_bounds__(256) void scan1_kernel(
    const int* __restrict__ deg, int* __restrict__ exloc, int* __restrict__ bsum)
{
  __shared__ int s[256];
  int i = blockIdx.x * 256 + threadIdx.x;
  int v = (i < NNODES) ? deg[i] : 0;
  s[threadIdx.x] = v;
  __syncthreads();
#pragma unroll
  for (int off = 1; off < 256; off <<= 1) {
    int t = (threadIdx.x >= off) ? s[threadIdx.x - off] : 0;
    __syncthreads();
    s[threadIdx.x] += t;
    __syncthreads();
  }
  if (i < NNODES) exloc[i] = s[threadIdx.x] - v;
  if (threadIdx.x == 255) bsum[blockIdx.x] = s[255];
}

__global__ __launch_bounds__(512) void scan2_kernel(int* __restrict__ bsum)
{
  __shared__ int s[512];
  int v = (threadIdx.x < NB_SCAN) ? bsum[threadIdx.x] : 0;
  s[threadIdx.x] = v;
  __syncthreads();
#pragma unroll
  for (int off = 1; off < 512; off <<= 1) {
    int t = (threadIdx.x >= off) ? s[threadIdx.x - off] : 0;
    __syncthreads();
    s[threadIdx.x] += t;
    __syncthreads();
  }
  if (threadIdx.x < NB_SCAN) bsum[threadIdx.x] = s[threadIdx.x] - v;
}

__global__ __launch_bounds__(256) void scan3_kernel(
    const int* __restrict__ exloc, const int* __restrict__ bsum,
    int* __restrict__ row_ptr, int* __restrict__ row_fill)
{
  int i = blockIdx.x * 256 + threadIdx.x;
  if (i < NNODES) {
    int v = exloc[i] + bsum[blockIdx.x];
    row_ptr[i] = v;
    row_fill[i] = v;
  }
  if (i == 0) row_ptr[NNODES] = NEDGES;
}

// XCD-sharded fill: block (chunk, shard); shard = blockIdx & 7 follows the
// round-robin block->XCD mapping, so each ~800KB epack window is written by a
// single XCD's L2 (one dirty copy, full lines, one writeback). Correct under
// ANY block->XCD mapping (filter is by dst value).
__global__ __launch_bounds__(256) void fill_kernel(
    const int* __restrict__ ei, const float* __restrict__ ew,
    int* __restrict__ row_fill, unsigned int* __restrict__ epack)
{
  int chunk = blockIdx.x >> 3;
  int shard = blockIdx.x & 7;
  int base = chunk * FILL_CHUNK;
  for (int t = threadIdx.x; t < FILL_CHUNK; t += 256) {
    int e = base + t;
    if (e >= NEDGES) break;
    int d = ei[NEDGES + e];
    if ((unsigned)d / SHARD == (unsigned)shard) {
      int p = atomicAdd(&row_fill[d], 1);
      epack[p] = pack_edge(ei[e], ew[e]);
    }
  }
}

// ---------------- graph pointer (batch sorted) ----------------
__global__ __launch_bounds__(256) void gptr_kernel(
    const int* __restrict__ batch, int* __restrict__ gptr)
{
  int i = blockIdx.x * 256 + threadIdx.x;
  if (i >= NNODES) return;
  int b = batch[i];
  int bn = (i + 1 < NNODES) ? batch[i + 1] : NGRAPH;
  for (int g = b + 1; g <= bn; g++) gptr[g] = i + 1;
  if (i == 0) for (int g = 0; g <= b; g++) gptr[g] = 0;
}

// ---------------- bf16 gather aggregation, high-MLP ----------------
// agg128: wave per node, quarter-split, 4-deep unroll -> 16 rows in flight/wave.
__global__ __launch_bounds__(256) void agg128_kernel(
    const int* __restrict__ row_ptr, const unsigned int* __restrict__ epack,
    const unsigned short* __restrict__ x, unsigned short* __restrict__ agg)
{
  int node = blockIdx.x * 4 + (threadIdx.x >> 6);
  int lane = threadIdx.x & 63;
  if (node >= NNODES) return;
  int q = lane >> 4, sl = lane & 15;
  int s = row_ptr[node], e = row_ptr[node + 1];
  float acc[8];
#pragma unroll
  for (int j = 0; j < 8; j++) acc[j] = 0.f;

  for (int i = s + q; i < e; i += 16) {
    unsigned int p0 = epack[i];
    unsigned int p1 = (i + 4  < e) ? epack[i + 4]  : 0u;
    unsigned int p2 = (i + 8  < e) ? epack[i + 8]  : 0u;
    unsigned int p3 = (i + 12 < e) ? epack[i + 12] : 0u;
    int s0, s1, s2, s3; float w0, w1, w2, w3;
    unpack_edge(p0, s0, w0);
    unpack_edge(p1, s1, w1);
    unpack_edge(p2, s2, w2);
    unpack_edge(p3, s3, w3);
    ushort8 r0 = *(const ushort8*)(x + (size_t)s0 * 128 + sl * 8);
    ushort8 r1 = *(const ushort8*)(x + (size_t)s1 * 128 + sl * 8);
    ushort8 r2 = *(const ushort8*)(x + (size_t)s2 * 128 + sl * 8);
    ushort8 r3 = *(const ushort8*)(x + (size_t)s3 * 128 + sl * 8);
#pragma unroll
    for (int j = 0; j < 8; j++)
      acc[j] += w0 * b2f(r0[j]) + w1 * b2f(r1[j]) +
                w2 * b2f(r2[j]) + w3 * b2f(r3[j]);
  }
#pragma unroll
  for (int j = 0; j < 8; j++) {
    acc[j] += __shfl_xor(acc[j], 16, 64);
    acc[j] += __shfl_xor(acc[j], 32, 64);
  }
  if (q == 0) {
    ushort8 o;
#pragma unroll
    for (int j = 0; j < 8; j++) o[j] = f2b(acc[j]);
    *(ushort8*)(agg + (size_t)node * 128 + sl * 8) = o;
  }
}

// agg64: wave per node, eighth-split, 2-deep unroll -> 16 rows in flight/wave.
__global__ __launch_bounds__(256) void agg64_kernel(
    const int* __restrict__ row_ptr, const unsigned int* __restrict__ epack,
    const unsigned short* __restrict__ x, unsigned short* __restrict__ agg)
{
  int node = blockIdx.x * 4 + (threadIdx.x >> 6);
  int lane = threadIdx.x & 63;
  if (node >= NNODES) return;
  int q = lane >> 3, sl = lane & 7;
  int s = row_ptr[node], e = row_ptr[node + 1];
  float acc[8];
#pragma unroll
  for (int j = 0; j < 8; j++) acc[j] = 0.f;

  for (int i = s + q; i < e; i += 16) {
    unsigned int p0 = epack[i];
    unsigned int p1 = (i + 8 < e) ? epack[i + 8] : 0u;
    int s0, s1; float w0, w1;
    unpack_edge(p0, s0, w0);
    unpack_edge(p1, s1, w1);
    ushort8 r0 = *(const ushort8*)(x + (size_t)s0 * 64 + sl * 8);
    ushort8 r1 = *(const ushort8*)(x + (size_t)s1 * 64 + sl * 8);
#pragma unroll
    for (int j = 0; j < 8; j++)
      acc[j] += w0 * b2f(r0[j]) + w1 * b2f(r1[j]);
  }
#pragma unroll
  for (int j = 0; j < 8; j++) {
    acc[j] += __shfl_xor(acc[j], 8, 64);
    acc[j] += __shfl_xor(acc[j], 16, 64);
    acc[j] += __shfl_xor(acc[j], 32, 64);
  }
  if (q == 0) {
    ushort8 o;
#pragma unroll
    for (int j = 0; j < 8; j++) o[j] = f2b(acc[j]);
    *(ushort8*)(agg + (size_t)node * 64 + sl * 8) = o;
  }
}

// ---------------- LDS-free MFMA bf16 GEMM ----------------
template <int KDIM, int HOUT, int MT, bool DUAL, bool RELU>
__global__ __launch_bounds__(256) void mfma_gemm(
    const unsigned short* __restrict__ A1, const unsigned short* __restrict__ W1,
    const unsigned short* __restrict__ A2, const unsigned short* __restrict__ W2,
    const float* __restrict__ bias, unsigned short* __restrict__ out)
{
  constexpr int NT2 = HOUT / 16;
  constexpr int KC = KDIM / 32;
  const int wave = threadIdx.x >> 6, lane = threadIdx.x & 63;
  const int quad = lane >> 4, l16 = lane & 15;
  const int n0 = (blockIdx.x * 4 + wave) * (MT * 16);

  f32x4 acc[MT][NT2];
#pragma unroll
  for (int m = 0; m < MT; m++)
#pragma unroll
    for (int t = 0; t < NT2; t++) acc[m][t] = (f32x4){0.f, 0.f, 0.f, 0.f};

  int nodes[MT];
#pragma unroll
  for (int m = 0; m < MT; m++) {
    int nd = n0 + m * 16 + l16;
    nodes[m] = nd < NNODES ? nd : NNODES - 1;
  }

#pragma unroll
  for (int c = 0; c < KC; c++) {
    short8 bfr[NT2];
#pragma unroll
    for (int t = 0; t < NT2; t++)
      bfr[t] = *(const short8*)(W1 + ((size_t)(c * 4 + quad) * HOUT + t * 16 + l16) * 8);
#pragma unroll
    for (int m = 0; m < MT; m++) {
      short8 af = *(const short8*)(A1 + (size_t)nodes[m] * KDIM + c * 32 + quad * 8);
#pragma unroll
      for (int t = 0; t < NT2; t++)
        acc[m][t] = __builtin_amdgcn_mfma_f32_16x16x32_bf16(af, bfr[t], acc[m][t], 0, 0, 0);
    }
    if (DUAL) {
#pragma unroll
      for (int t = 0; t < NT2; t++)
        bfr[t] = *(const short8*)(W2 + ((size_t)(c * 4 + quad) * HOUT + t * 16 + l16) * 8);
#pragma unroll
      for (int m = 0; m < MT; m++) {
        short8 af = *(const short8*)(A2 + (size_t)nodes[m] * KDIM + c * 32 + quad * 8);
#pragma unroll
        for (int t = 0; t < NT2; t++)
          acc[m][t] = __builtin_amdgcn_mfma_f32_16x16x32_bf16(af, bfr[t], acc[m][t], 0, 0, 0);
      }
    }
  }

#pragma unroll
  for (int m = 0; m < MT; m++) {
    int rowbase = n0 + m * 16 + quad * 4;
#pragma unroll
    for (int t = 0; t < NT2; t++) {
      float b = bias[t * 16 + l16];
#pragma unroll
      for (int r = 0; r < 4; r++) {
        int nd = rowbase + r;
        if (nd < NNODES) {
          float v = acc[m][t][r] + b;
          if (RELU) v = fmaxf(v, 0.f);
          out[(size_t)nd * HOUT + t * 16 + l16] = f2b(v);
        }
      }
    }
  }
}

// ---------------- readout: per-graph block reduction ----------------
__global__ __launch_bounds__(256) void readout_reduce_kernel(
    const unsigned short* __restrict__ h, const float* __restrict__ Wr2,
    const float* __restrict__ br2, const int* __restrict__ gptr,
    float* __restrict__ out)
{
  __shared__ float wsum[4];
  int g = blockIdx.x;
  int s = gptr[g], e = gptr[g + 1];
  int wave = threadIdx.x >> 6, lane = threadIdx.x & 63;
  float w2 = Wr2[lane];
  float acc = 0.f;
  for (int n = s + wave; n < e; n += 4)
    acc += b2f(h[(size_t)n * 64 + lane]) * w2;
#pragma unroll
  for (int off = 32; off >= 1; off >>= 1) acc += __shfl_xor(acc, off, 64);
  if (lane == 0) wsum[wave] = acc;
  __syncthreads();
  if (threadIdx.x == 0) {
    float cnt = (float)(e - s);
    float sum = wsum[0] + wsum[1] + wsum[2] + wsum[3] + cnt * br2[0];
    out[g] = sum / fmaxf(cnt, 1.f);
  }
}

// ---------------- launch ----------------
extern "C" void kernel_launch(void* const* d_in, const int* in_sizes, int n_in,
                              void* d_out, int out_size, void* d_ws, size_t ws_size,
                              hipStream_t stream)
{
  const float* x      = (const float*)d_in[0];
  const int*   ei     = (const int*)d_in[1];
  const float* ew     = (const float*)d_in[2];
  const int*   batch  = (const int*)d_in[3];
  const float* Wroot0 = (const float*)d_in[4];
  const float* Wrel0  = (const float*)d_in[5];
  const float* b0     = (const float*)d_in[6];
  const float* WrootR = (const float*)d_in[7];
  const float* WrelR  = (const float*)d_in[8];
  const float* bR     = (const float*)d_in[9];
  const float* Wr1    = (const float*)d_in[10];
  const float* br1    = (const float*)d_in[11];
  const float* Wr2    = (const float*)d_in[12];
  const float* br2    = (const float*)d_in[13];

  char* ws = (char*)d_ws;
  unsigned short* wp   = (unsigned short*)ws;                 // 122880 bf16, pad to 131072
  unsigned short* xb   = wp + 131072;                         // N*64 bf16
  unsigned short* agg0 = xb + (size_t)NNODES * 64;            // N*64 bf16
  unsigned short* bufA = agg0 + (size_t)NNODES * 64;          // N*128 bf16
  unsigned short* bufB = bufA + (size_t)NNODES * 128;         // N*128 bf16
  unsigned short* hbuf = bufB + (size_t)NNODES * 128;         // N*64 bf16
  int*  deg      = (int*)(hbuf + (size_t)NNODES * 64);
  int*  exloc    = deg + NNODES;
  int*  row_ptr  = exloc + NNODES;
  int*  row_fill = row_ptr + NNODES + 2;
  int*  bsum     = row_fill + NNODES;
  int*  gptr     = bsum + 512;
  unsigned int* epack = (unsigned int*)(gptr + NGRAPH + 2);   // E uint = 6.4MB

  prepack_kernel<<<60, 256, 0, stream>>>(Wrel0, Wroot0, WrelR, WrootR, Wr1, wp);
  cvt_x_kernel<<<(NNODES * 64 / 4 + 255) / 256, 256, 0, stream>>>(x, xb);

  const unsigned short* pWrel0  = wp;
  const unsigned short* pWroot0 = wp + 8192;
  const unsigned short* pWrelR  = wp + 16384;
  const unsigned short* pWrootR = wp + 65536;
  const unsigned short* pWr1    = wp + 114688;

  // CSR (by dst) + graph ptr
  hipMemsetAsync(deg, 0, NNODES * sizeof(int), stream);
  hist_kernel<<<(NEDGES + 255) / 256, 256, 0, stream>>>(ei, deg);
  scan1_kernel<<<NB_SCAN, 256, 0, stream>>>(deg, exloc, bsum);
  scan2_kernel<<<1, 512, 0, stream>>>(bsum);
  scan3_kernel<<<NB_SCAN, 256, 0, stream>>>(exloc, bsum, row_ptr, row_fill);
  fill_kernel<<<FILL_NCHUNK * 8, 256, 0, stream>>>(ei, ew, row_fill, epack);
  gptr_kernel<<<(NNODES + 255) / 256, 256, 0, stream>>>(batch, gptr);

  // layer 0: 64 -> 128
  agg64_kernel<<<(NNODES + 3) / 4, 256, 0, stream>>>(row_ptr, epack, xb, agg0);
  mfma_gemm<64, 128, 2, true, false><<<(NNODES + 127) / 128, 256, 0, stream>>>(
      agg0, pWrel0, xb, pWroot0, b0, bufB);

  // layers 1..3: 128 -> 128
  unsigned short* bufs[2] = { bufB, bufA };
  for (int l = 0; l < 3; l++) {
    unsigned short* in  = bufs[l & 1];
    unsigned short* agg = bufs[(l & 1) ^ 1];
    agg128_kernel<<<(NNODES + 3) / 4, 256, 0, stream>>>(row_ptr, epack, in, agg);
    mfma_gemm<128, 128, 2, true, false><<<(NNODES + 127) / 128, 256, 0, stream>>>(
        agg, pWrelR + l * 16384, in, pWrootR + l * 16384, bR + l * 128, agg);
  }
  // y3 in bufA

  // readout
  mfma_gemm<128, 64, 4, false, true><<<(NNODES + 255) / 256, 256, 0, stream>>>(
      bufA, pWr1, nullptr, nullptr, br1, hbuf);
  readout_reduce_kernel<<<NGRAPH, 256, 0, stream>>>(hbuf, Wr2, br2, gptr, (float*)d_out);
}